// Round 4
// baseline (2215.090 us; speedup 1.0000x reference)
//
#include <hip/hip_runtime.h>
#include <hip/hip_bf16.h>
#include <math.h>

#define B_  4
#define T_  2048
#define D_  1024
#define H_  16
#define HD_ 64
#define M_  8192   // B_*T_

// ---------------------------------------------------------------------------
// QKV projection: out[b,h,t,e] = (sum_d x[b,t,d]*W[h,d,e] + bias[h,e]) * scl
// scl = 8 (= sqrt(64), the reference's score scale) folded into q only.
// grid (M_/128, H_, 3), block 256 (16x16), thread tile 8x4, K-chunk 32.
// ---------------------------------------------------------------------------
__global__ __launch_bounds__(256) void qkv_proj(
    const float* __restrict__ x,
    const float* __restrict__ Wq, const float* __restrict__ bq,
    const float* __restrict__ Wk, const float* __restrict__ bk,
    const float* __restrict__ Wv, const float* __restrict__ bv,
    float* __restrict__ qws, float* __restrict__ kws, float* __restrict__ vws)
{
    const int z = blockIdx.z;
    const float* W    = (z==0) ? Wq : (z==1) ? Wk : Wv;
    const float* bias = (z==0) ? bq : (z==1) ? bk : bv;
    float*       out  = (z==0) ? qws : (z==1) ? kws : vws;
    const int h   = blockIdx.y;
    const int m0  = blockIdx.x * 128;
    const int tid = threadIdx.x;
    const int tx  = tid & 15, ty = tid >> 4;

    __shared__ float At[32][132];  // [k][m] transposed A tile
    __shared__ float Bs[32][68];   // [k][n]

    float acc[8][4];
#pragma unroll
    for (int i=0;i<8;i++)
#pragma unroll
      for (int j=0;j<4;j++) acc[i][j]=0.f;

    const int ar  = tid >> 1;        // 0..127 row in tile
    const int ac0 = (tid & 1) * 16;  // k-col base
    const int br  = tid >> 3;        // 0..31 k-row
    const int bc0 = (tid & 7) * 8;   // n-col base

    const float* Wh = W + (size_t)h * D_ * HD_;

    for (int k0 = 0; k0 < D_; k0 += 32) {
        const float* xp = x + (size_t)(m0 + ar) * D_ + k0 + ac0;
        float4 a0 = *(const float4*)(xp + 0);
        float4 a1 = *(const float4*)(xp + 4);
        float4 a2 = *(const float4*)(xp + 8);
        float4 a3 = *(const float4*)(xp + 12);
        const float* wp = Wh + (size_t)(k0 + br) * HD_ + bc0;
        float4 b0 = *(const float4*)(wp + 0);
        float4 b1 = *(const float4*)(wp + 4);
        __syncthreads();  // previous chunk's compute done before overwrite
        At[ac0+ 0][ar]=a0.x; At[ac0+ 1][ar]=a0.y; At[ac0+ 2][ar]=a0.z; At[ac0+ 3][ar]=a0.w;
        At[ac0+ 4][ar]=a1.x; At[ac0+ 5][ar]=a1.y; At[ac0+ 6][ar]=a1.z; At[ac0+ 7][ar]=a1.w;
        At[ac0+ 8][ar]=a2.x; At[ac0+ 9][ar]=a2.y; At[ac0+10][ar]=a2.z; At[ac0+11][ar]=a2.w;
        At[ac0+12][ar]=a3.x; At[ac0+13][ar]=a3.y; At[ac0+14][ar]=a3.z; At[ac0+15][ar]=a3.w;
        *(float4*)&Bs[br][bc0]   = b0;
        *(float4*)&Bs[br][bc0+4] = b1;
        __syncthreads();
#pragma unroll
        for (int k=0;k<32;k++){
            float4 qa0 = *(const float4*)&At[k][ty*8];
            float4 qa1 = *(const float4*)&At[k][ty*8+4];
            float4 qb  = *(const float4*)&Bs[k][tx*4];
            float aa[8]={qa0.x,qa0.y,qa0.z,qa0.w,qa1.x,qa1.y,qa1.z,qa1.w};
            float bb[4]={qb.x,qb.y,qb.z,qb.w};
#pragma unroll
            for (int i=0;i<8;i++)
#pragma unroll
                for (int j=0;j<4;j++)
                    acc[i][j] = fmaf(aa[i], bb[j], acc[i][j]);
        }
    }
    const float scale = (z==0) ? 8.0f : 1.0f;
    float bj[4];
#pragma unroll
    for (int j=0;j<4;j++) bj[j] = bias[h*HD_ + tx*4 + j];
#pragma unroll
    for (int i=0;i<8;i++){
        int m = m0 + ty*8 + i;
        int b = m >> 11, t = m & (T_-1);
        float4 v;
        v.x = (acc[i][0]+bj[0])*scale;
        v.y = (acc[i][1]+bj[1])*scale;
        v.z = (acc[i][2]+bj[2])*scale;
        v.w = (acc[i][3]+bj[3])*scale;
        *(float4*)(out + ((size_t)(b*H_ + h)*T_ + t)*HD_ + tx*4) = v;
    }
}

// ---------------------------------------------------------------------------
// Flash attention (fp32). One block = one (b,h) x 64 query rows.
// 64x64 KV tiles, online softmax. P reuses K's LDS buffer.
// grid: 2048 blocks ordered work-descending; block 256 (16x16), 4x4/thread.
// ---------------------------------------------------------------------------
__global__ __launch_bounds__(256) void attn(
    const float* __restrict__ qws, const float* __restrict__ kws,
    const float* __restrict__ vws, float* __restrict__ att,
    const int* __restrict__ maskp)
{
    const int bid = blockIdx.x;
    const int qb  = 31 - (bid >> 6);   // big blocks first (load balance)
    const int bh  = bid & 63;
    const int b   = bh >> 4, h = bh & 15;
    const int tid = threadIdx.x;
    const int tx  = tid & 15, ty = tid >> 4;
    const int domask = maskp[0];

    __shared__ float Qs[64][68];
    __shared__ float KP[64][68];   // K tile, then reused for P
    __shared__ float Vt[64][68];   // V transposed: [d][c]

    const float* qp = qws + ((size_t)bh*T_ + qb*64)*HD_;
    const float* kp = kws + (size_t)bh*T_*HD_;
    const float* vp = vws + (size_t)bh*T_*HD_;

    {   // load Q tile
        int r = tid>>2, c0 = (tid&3)*16;
        const float* src = qp + r*HD_ + c0;
        float4 v0=*(const float4*)(src+0), v1=*(const float4*)(src+4);
        float4 v2=*(const float4*)(src+8), v3=*(const float4*)(src+12);
        *(float4*)&Qs[r][c0+ 0]=v0; *(float4*)&Qs[r][c0+ 4]=v1;
        *(float4*)&Qs[r][c0+ 8]=v2; *(float4*)&Qs[r][c0+12]=v3;
    }

    float o[4][4];
    float m_run[4], l_run[4];
#pragma unroll
    for (int i=0;i<4;i++){
        m_run[i] = -INFINITY; l_run[i] = 0.f;
#pragma unroll
        for (int j=0;j<4;j++) o[i][j] = 0.f;
    }

    const int kv_end = domask ? qb : 31;
    for (int kv = 0; kv <= kv_end; ++kv){
        int r = tid>>2, c0 = (tid&3)*16;
        const float* ksrc = kp + (size_t)(kv*64+r)*HD_ + c0;
        float4 k0=*(const float4*)(ksrc+0), k1=*(const float4*)(ksrc+4);
        float4 k2=*(const float4*)(ksrc+8), k3=*(const float4*)(ksrc+12);
        const float* vsrc = vp + (size_t)(kv*64+r)*HD_ + c0;
        float4 w0=*(const float4*)(vsrc+0), w1=*(const float4*)(vsrc+4);
        float4 w2=*(const float4*)(vsrc+8), w3=*(const float4*)(vsrc+12);
        __syncthreads();  // previous PV reads of KP/Vt complete
        *(float4*)&KP[r][c0+ 0]=k0; *(float4*)&KP[r][c0+ 4]=k1;
        *(float4*)&KP[r][c0+ 8]=k2; *(float4*)&KP[r][c0+12]=k3;
        Vt[c0+ 0][r]=w0.x; Vt[c0+ 1][r]=w0.y; Vt[c0+ 2][r]=w0.z; Vt[c0+ 3][r]=w0.w;
        Vt[c0+ 4][r]=w1.x; Vt[c0+ 5][r]=w1.y; Vt[c0+ 6][r]=w1.z; Vt[c0+ 7][r]=w1.w;
        Vt[c0+ 8][r]=w2.x; Vt[c0+ 9][r]=w2.y; Vt[c0+10][r]=w2.z; Vt[c0+11][r]=w2.w;
        Vt[c0+12][r]=w3.x; Vt[c0+13][r]=w3.y; Vt[c0+14][r]=w3.z; Vt[c0+15][r]=w3.w;
        __syncthreads();

        // S = Q K^T  (4x4 per thread)
        float s[4][4];
#pragma unroll
        for (int i=0;i<4;i++)
#pragma unroll
            for (int j=0;j<4;j++) s[i][j]=0.f;
#pragma unroll
        for (int e=0;e<64;e+=4){
            float4 qv[4], kv4[4];
#pragma unroll
            for (int i=0;i<4;i++) qv[i]  = *(const float4*)&Qs[ty*4+i][e];
#pragma unroll
            for (int j=0;j<4;j++) kv4[j] = *(const float4*)&KP[tx*4+j][e];
#pragma unroll
            for (int i=0;i<4;i++)
#pragma unroll
                for (int j=0;j<4;j++){
                    s[i][j] = fmaf(qv[i].x, kv4[j].x, s[i][j]);
                    s[i][j] = fmaf(qv[i].y, kv4[j].y, s[i][j]);
                    s[i][j] = fmaf(qv[i].z, kv4[j].z, s[i][j]);
                    s[i][j] = fmaf(qv[i].w, kv4[j].w, s[i][j]);
                }
        }
        if (domask && kv == qb){
#pragma unroll
            for (int i=0;i<4;i++)
#pragma unroll
                for (int j=0;j<4;j++)
                    if (tx*4+j > ty*4+i) s[i][j] = -INFINITY;
        }

        // online softmax
        float p[4][4];
#pragma unroll
        for (int i=0;i<4;i++){
            float mloc = fmaxf(fmaxf(s[i][0],s[i][1]), fmaxf(s[i][2],s[i][3]));
            mloc = fmaxf(mloc, __shfl_xor(mloc,1));
            mloc = fmaxf(mloc, __shfl_xor(mloc,2));
            mloc = fmaxf(mloc, __shfl_xor(mloc,4));
            mloc = fmaxf(mloc, __shfl_xor(mloc,8));
            float mnew = fmaxf(m_run[i], mloc);
            float scl  = __expf(m_run[i] - mnew);  // exp(-inf)=0 on first tile
            m_run[i] = mnew;
            float rs = 0.f;
#pragma unroll
            for (int j=0;j<4;j++){ p[i][j] = __expf(s[i][j]-mnew); rs += p[i][j]; }
            rs += __shfl_xor(rs,1); rs += __shfl_xor(rs,2);
            rs += __shfl_xor(rs,4); rs += __shfl_xor(rs,8);
            l_run[i] = l_run[i]*scl + rs;
#pragma unroll
            for (int j=0;j<4;j++) o[i][j] *= scl;
        }
        __syncthreads();  // all S reads of KP done
#pragma unroll
        for (int i=0;i<4;i++)
#pragma unroll
            for (int j=0;j<4;j++) KP[ty*4+i][tx*4+j] = p[i][j];
        __syncthreads();

        // O += P V
#pragma unroll
        for (int c=0;c<64;c+=4){
            float4 pr[4], vr[4];
#pragma unroll
            for (int i=0;i<4;i++) pr[i] = *(const float4*)&KP[ty*4+i][c];
#pragma unroll
            for (int j=0;j<4;j++) vr[j] = *(const float4*)&Vt[tx*4+j][c];
#pragma unroll
            for (int i=0;i<4;i++)
#pragma unroll
                for (int j=0;j<4;j++){
                    o[i][j] = fmaf(pr[i].x, vr[j].x, o[i][j]);
                    o[i][j] = fmaf(pr[i].y, vr[j].y, o[i][j]);
                    o[i][j] = fmaf(pr[i].z, vr[j].z, o[i][j]);
                    o[i][j] = fmaf(pr[i].w, vr[j].w, o[i][j]);
                }
        }
    }

#pragma unroll
    for (int i=0;i<4;i++){
        float inv = 1.0f / l_run[i];
        int t = qb*64 + ty*4 + i;
        float4 v = { o[i][0]*inv, o[i][1]*inv, o[i][2]*inv, o[i][3]*inv };
        *(float4*)(att + ((size_t)b*T_ + t)*D_ + h*HD_ + tx*4) = v;
    }
}

// ---------------------------------------------------------------------------
// Output projection: out = att @ Wo + bo.  grid (M_/128, D_/64), block 256.
// ---------------------------------------------------------------------------
__global__ __launch_bounds__(256) void oproj(
    const float* __restrict__ A, const float* __restrict__ Wo,
    const float* __restrict__ bo, float* __restrict__ out)
{
    const int n0  = blockIdx.y * 64;
    const int m0  = blockIdx.x * 128;
    const int tid = threadIdx.x;
    const int tx  = tid & 15, ty = tid >> 4;

    __shared__ float At[32][132];
    __shared__ float Bs[32][68];

    float acc[8][4];
#pragma unroll
    for (int i=0;i<8;i++)
#pragma unroll
      for (int j=0;j<4;j++) acc[i][j]=0.f;

    const int ar  = tid >> 1;
    const int ac0 = (tid & 1) * 16;
    const int br  = tid >> 3;
    const int bc0 = (tid & 7) * 8;

    for (int k0 = 0; k0 < D_; k0 += 32) {
        const float* ap = A + (size_t)(m0 + ar) * D_ + k0 + ac0;
        float4 a0 = *(const float4*)(ap + 0);
        float4 a1 = *(const float4*)(ap + 4);
        float4 a2 = *(const float4*)(ap + 8);
        float4 a3 = *(const float4*)(ap + 12);
        const float* wp = Wo + (size_t)(k0 + br) * D_ + n0 + bc0;
        float4 b0 = *(const float4*)(wp + 0);
        float4 b1 = *(const float4*)(wp + 4);
        __syncthreads();
        At[ac0+ 0][ar]=a0.x; At[ac0+ 1][ar]=a0.y; At[ac0+ 2][ar]=a0.z; At[ac0+ 3][ar]=a0.w;
        At[ac0+ 4][ar]=a1.x; At[ac0+ 5][ar]=a1.y; At[ac0+ 6][ar]=a1.z; At[ac0+ 7][ar]=a1.w;
        At[ac0+ 8][ar]=a2.x; At[ac0+ 9][ar]=a2.y; At[ac0+10][ar]=a2.z; At[ac0+11][ar]=a2.w;
        At[ac0+12][ar]=a3.x; At[ac0+13][ar]=a3.y; At[ac0+14][ar]=a3.z; At[ac0+15][ar]=a3.w;
        *(float4*)&Bs[br][bc0]   = b0;
        *(float4*)&Bs[br][bc0+4] = b1;
        __syncthreads();
#pragma unroll
        for (int k=0;k<32;k++){
            float4 qa0 = *(const float4*)&At[k][ty*8];
            float4 qa1 = *(const float4*)&At[k][ty*8+4];
            float4 qb  = *(const float4*)&Bs[k][tx*4];
            float aa[8]={qa0.x,qa0.y,qa0.z,qa0.w,qa1.x,qa1.y,qa1.z,qa1.w};
            float bb[4]={qb.x,qb.y,qb.z,qb.w};
#pragma unroll
            for (int i=0;i<8;i++)
#pragma unroll
                for (int j=0;j<4;j++)
                    acc[i][j] = fmaf(aa[i], bb[j], acc[i][j]);
        }
    }
    float bj[4];
#pragma unroll
    for (int j=0;j<4;j++) bj[j] = bo[n0 + tx*4 + j];
#pragma unroll
    for (int i=0;i<8;i++){
        int m = m0 + ty*8 + i;
        float4 v;
        v.x = acc[i][0]+bj[0];
        v.y = acc[i][1]+bj[1];
        v.z = acc[i][2]+bj[2];
        v.w = acc[i][3]+bj[3];
        *(float4*)(out + (size_t)m*D_ + n0 + tx*4) = v;
    }
}

extern "C" void kernel_launch(void* const* d_in, const int* in_sizes, int n_in,
                              void* d_out, int out_size, void* d_ws, size_t ws_size,
                              hipStream_t stream)
{
    const float* x  = (const float*)d_in[0];
    const float* Wq = (const float*)d_in[1];
    const float* bq = (const float*)d_in[2];
    const float* Wk = (const float*)d_in[3];
    const float* bk = (const float*)d_in[4];
    const float* Wv = (const float*)d_in[5];
    const float* bv = (const float*)d_in[6];
    const float* Wo = (const float*)d_in[7];
    const float* bo = (const float*)d_in[8];
    const int* mask = (const int*)d_in[9];
    float* out = (float*)d_out;

    float* qws = (float*)d_ws;                       // [B,H,T,HD] 32MB (q*8)
    float* kws = qws + (size_t)8*1024*1024;          // 32MB
    float* vws = kws + (size_t)8*1024*1024;          // 32MB
    float* att = vws + (size_t)8*1024*1024;          // [B,T,D] 32MB

    qkv_proj<<<dim3(M_/128, H_, 3), 256, 0, stream>>>(x, Wq, bq, Wk, bk, Wv, bv,
                                                      qws, kws, vws);
    attn<<<dim3(2048), 256, 0, stream>>>(qws, kws, vws, att, mask);
    oproj<<<dim3(M_/128, D_/64), 256, 0, stream>>>(att, Wo, bo, out);
}

// Round 5
// 1549.734 us; speedup vs baseline: 1.4293x; 1.4293x over previous
//
#include <hip/hip_runtime.h>
#include <hip/hip_bf16.h>
#include <math.h>

#define B_  4
#define T_  2048
#define D_  1024
#define H_  16
#define HD_ 64
#define M_  8192   // B_*T_

// ---------------------------------------------------------------------------
// QKV projection: out[b,h,t,e] = (sum_d x[b,t,d]*W[h,d,e] + bias[h,e]) * scl
// scl = 8 (= sqrt(64), the reference's score scale) folded into q only.
// grid (M_/128, H_, 3), block 256 (16x16), thread tile 8x4, K-chunk 32.
// (unchanged this round)
// ---------------------------------------------------------------------------
__global__ __launch_bounds__(256) void qkv_proj(
    const float* __restrict__ x,
    const float* __restrict__ Wq, const float* __restrict__ bq,
    const float* __restrict__ Wk, const float* __restrict__ bk,
    const float* __restrict__ Wv, const float* __restrict__ bv,
    float* __restrict__ qws, float* __restrict__ kws, float* __restrict__ vws)
{
    const int z = blockIdx.z;
    const float* W    = (z==0) ? Wq : (z==1) ? Wk : Wv;
    const float* bias = (z==0) ? bq : (z==1) ? bk : bv;
    float*       out  = (z==0) ? qws : (z==1) ? kws : vws;
    const int h   = blockIdx.y;
    const int m0  = blockIdx.x * 128;
    const int tid = threadIdx.x;
    const int tx  = tid & 15, ty = tid >> 4;

    __shared__ float At[32][132];  // [k][m] transposed A tile
    __shared__ float Bs[32][68];   // [k][n]

    float acc[8][4];
#pragma unroll
    for (int i=0;i<8;i++)
#pragma unroll
      for (int j=0;j<4;j++) acc[i][j]=0.f;

    const int ar  = tid >> 1;        // 0..127 row in tile
    const int ac0 = (tid & 1) * 16;  // k-col base
    const int br  = tid >> 3;        // 0..31 k-row
    const int bc0 = (tid & 7) * 8;   // n-col base

    const float* Wh = W + (size_t)h * D_ * HD_;

    for (int k0 = 0; k0 < D_; k0 += 32) {
        const float* xp = x + (size_t)(m0 + ar) * D_ + k0 + ac0;
        float4 a0 = *(const float4*)(xp + 0);
        float4 a1 = *(const float4*)(xp + 4);
        float4 a2 = *(const float4*)(xp + 8);
        float4 a3 = *(const float4*)(xp + 12);
        const float* wp = Wh + (size_t)(k0 + br) * HD_ + bc0;
        float4 b0 = *(const float4*)(wp + 0);
        float4 b1 = *(const float4*)(wp + 4);
        __syncthreads();  // previous chunk's compute done before overwrite
        At[ac0+ 0][ar]=a0.x; At[ac0+ 1][ar]=a0.y; At[ac0+ 2][ar]=a0.z; At[ac0+ 3][ar]=a0.w;
        At[ac0+ 4][ar]=a1.x; At[ac0+ 5][ar]=a1.y; At[ac0+ 6][ar]=a1.z; At[ac0+ 7][ar]=a1.w;
        At[ac0+ 8][ar]=a2.x; At[ac0+ 9][ar]=a2.y; At[ac0+10][ar]=a2.z; At[ac0+11][ar]=a2.w;
        At[ac0+12][ar]=a3.x; At[ac0+13][ar]=a3.y; At[ac0+14][ar]=a3.z; At[ac0+15][ar]=a3.w;
        *(float4*)&Bs[br][bc0]   = b0;
        *(float4*)&Bs[br][bc0+4] = b1;
        __syncthreads();
#pragma unroll
        for (int k=0;k<32;k++){
            float4 qa0 = *(const float4*)&At[k][ty*8];
            float4 qa1 = *(const float4*)&At[k][ty*8+4];
            float4 qb  = *(const float4*)&Bs[k][tx*4];
            float aa[8]={qa0.x,qa0.y,qa0.z,qa0.w,qa1.x,qa1.y,qa1.z,qa1.w};
            float bb[4]={qb.x,qb.y,qb.z,qb.w};
#pragma unroll
            for (int i=0;i<8;i++)
#pragma unroll
                for (int j=0;j<4;j++)
                    acc[i][j] = fmaf(aa[i], bb[j], acc[i][j]);
        }
    }
    const float scale = (z==0) ? 8.0f : 1.0f;
    float bj[4];
#pragma unroll
    for (int j=0;j<4;j++) bj[j] = bias[h*HD_ + tx*4 + j];
#pragma unroll
    for (int i=0;i<8;i++){
        int m = m0 + ty*8 + i;
        int b = m >> 11, t = m & (T_-1);
        float4 v;
        v.x = (acc[i][0]+bj[0])*scale;
        v.y = (acc[i][1]+bj[1])*scale;
        v.z = (acc[i][2]+bj[2])*scale;
        v.w = (acc[i][3]+bj[3])*scale;
        *(float4*)(out + ((size_t)(b*H_ + h)*T_ + t)*HD_ + tx*4) = v;
    }
}

// ---------------------------------------------------------------------------
// Flash attention (fp32), bank-conflict-free LDS layouts.
// K,V tiles: row-major stride 64, XOR-swizzled float4 blocks p = c ^ (r>>2).
//   - staging writes land at wave64-b128 floor
//   - QK^T K-reads: 16 tx-rows -> blocks (e>>2)^tx -> distinct quads (floor)
//   - PV V-reads: row-major (no transpose!) blocks tx^cs -> floor
// Q,P: padded stride 68, float4 writes, broadcast reads (conflict-free).
// grid 2048 (big qb first); block 256 (16x16), 4x4/thread.
// ---------------------------------------------------------------------------
__global__ __launch_bounds__(256) void attn(
    const float* __restrict__ qws, const float* __restrict__ kws,
    const float* __restrict__ vws, float* __restrict__ att,
    const int* __restrict__ maskp)
{
    const int bid = blockIdx.x;
    const int qb  = 31 - (bid >> 6);   // big blocks first (load balance)
    const int bh  = bid & 63;
    const int b   = bh >> 4, h = bh & 15;
    const int tid = threadIdx.x;
    const int tx  = tid & 15, ty = tid >> 4;
    const int domask = maskp[0];

    __shared__ __align__(16) float KS[64*64];   // swizzled K tile
    __shared__ __align__(16) float Vs[64*64];   // swizzled V tile (row-major)
    __shared__ __align__(16) float Qs[64*68];   // padded Q tile
    __shared__ __align__(16) float Ps[64*68];   // padded P tile

    const float* qp = qws + ((size_t)bh*T_ + qb*64)*HD_;
    const float* kp = kws + (size_t)bh*T_*HD_;
    const float* vp = vws + (size_t)bh*T_*HD_;

    const int r  = tid >> 2;          // 0..63 staging row
    const int q4 = (tid & 3) * 4;     // staging block base (blocks of 4 floats)
    const int fr = r >> 2;            // swizzle key for staging row

    {   // load Q tile (padded 68)
        const float* src = qp + r*HD_ + q4*4;
        float4 v0=*(const float4*)(src+0), v1=*(const float4*)(src+4);
        float4 v2=*(const float4*)(src+8), v3=*(const float4*)(src+12);
        *(float4*)&Qs[r*68 + q4*4 + 0]=v0; *(float4*)&Qs[r*68 + q4*4 + 4]=v1;
        *(float4*)&Qs[r*68 + q4*4 + 8]=v2; *(float4*)&Qs[r*68 + q4*4 +12]=v3;
    }

    float o[4][4];
    float m_run[4], l_run[4];
#pragma unroll
    for (int i=0;i<4;i++){
        m_run[i] = -INFINITY; l_run[i] = 0.f;
#pragma unroll
        for (int j=0;j<4;j++) o[i][j] = 0.f;
    }

    const int kv_end = domask ? qb : 31;
    for (int kv = 0; kv <= kv_end; ++kv){
        const float* ksrc = kp + (size_t)(kv*64+r)*HD_ + q4*4;
        float4 k0=*(const float4*)(ksrc+0), k1=*(const float4*)(ksrc+4);
        float4 k2=*(const float4*)(ksrc+8), k3=*(const float4*)(ksrc+12);
        const float* vsrc = vp + (size_t)(kv*64+r)*HD_ + q4*4;
        float4 w0=*(const float4*)(vsrc+0), w1=*(const float4*)(vsrc+4);
        float4 w2=*(const float4*)(vsrc+8), w3=*(const float4*)(vsrc+12);
        __syncthreads();  // prev tile's QK^T (KS) + PV (Vs,Ps) reads complete
        // swizzled writes: block c = q4+m at physical p = c ^ fr
        *(float4*)&KS[r*64 + 4*((q4+0)^fr)] = k0;
        *(float4*)&KS[r*64 + 4*((q4+1)^fr)] = k1;
        *(float4*)&KS[r*64 + 4*((q4+2)^fr)] = k2;
        *(float4*)&KS[r*64 + 4*((q4+3)^fr)] = k3;
        *(float4*)&Vs[r*64 + 4*((q4+0)^fr)] = w0;
        *(float4*)&Vs[r*64 + 4*((q4+1)^fr)] = w1;
        *(float4*)&Vs[r*64 + 4*((q4+2)^fr)] = w2;
        *(float4*)&Vs[r*64 + 4*((q4+3)^fr)] = w3;
        __syncthreads();

        // S = Q K^T  (4x4 per thread); K physical block = (e>>2) ^ tx
        float s[4][4];
#pragma unroll
        for (int i=0;i<4;i++)
#pragma unroll
            for (int j=0;j<4;j++) s[i][j]=0.f;
#pragma unroll
        for (int e=0;e<64;e+=4){
            const int koff = 4*((e>>2) ^ tx);
            float4 qv[4], kv4[4];
#pragma unroll
            for (int i=0;i<4;i++) qv[i]  = *(const float4*)&Qs[(ty*4+i)*68 + e];
#pragma unroll
            for (int j=0;j<4;j++) kv4[j] = *(const float4*)&KS[(tx*4+j)*64 + koff];
#pragma unroll
            for (int i=0;i<4;i++)
#pragma unroll
                for (int j=0;j<4;j++){
                    s[i][j] = fmaf(qv[i].x, kv4[j].x, s[i][j]);
                    s[i][j] = fmaf(qv[i].y, kv4[j].y, s[i][j]);
                    s[i][j] = fmaf(qv[i].z, kv4[j].z, s[i][j]);
                    s[i][j] = fmaf(qv[i].w, kv4[j].w, s[i][j]);
                }
        }
        if (domask && kv == qb){
#pragma unroll
            for (int i=0;i<4;i++)
#pragma unroll
                for (int j=0;j<4;j++)
                    if (tx*4+j > ty*4+i) s[i][j] = -INFINITY;
        }

        // online softmax (row groups of 16 lanes; xor masks stay in-group)
        float p[4][4];
#pragma unroll
        for (int i=0;i<4;i++){
            float mloc = fmaxf(fmaxf(s[i][0],s[i][1]), fmaxf(s[i][2],s[i][3]));
            mloc = fmaxf(mloc, __shfl_xor(mloc,1));
            mloc = fmaxf(mloc, __shfl_xor(mloc,2));
            mloc = fmaxf(mloc, __shfl_xor(mloc,4));
            mloc = fmaxf(mloc, __shfl_xor(mloc,8));
            float mnew = fmaxf(m_run[i], mloc);
            float scl  = __expf(m_run[i] - mnew);  // exp(-inf)=0 on first tile
            m_run[i] = mnew;
            float rs = 0.f;
#pragma unroll
            for (int j=0;j<4;j++){ p[i][j] = __expf(s[i][j]-mnew); rs += p[i][j]; }
            rs += __shfl_xor(rs,1); rs += __shfl_xor(rs,2);
            rs += __shfl_xor(rs,4); rs += __shfl_xor(rs,8);
            l_run[i] = l_run[i]*scl + rs;
#pragma unroll
            for (int j=0;j<4;j++) o[i][j] *= scl;
        }
        // P write: float4 per row (conflict-free)
#pragma unroll
        for (int i=0;i<4;i++){
            float4 pv4 = { p[i][0], p[i][1], p[i][2], p[i][3] };
            *(float4*)&Ps[(ty*4+i)*68 + tx*4] = pv4;
        }
        __syncthreads();

        // O += P V : o[i][j] += P[4ty+i][4cs+m] * V[4cs+m][4tx+j]
        // P reads broadcast; V physical block = tx ^ cs (conflict-free)
#pragma unroll
        for (int cs=0; cs<16; ++cs){
            const int voff = 4*(tx ^ cs);
            float4 pr[4], vv[4];
#pragma unroll
            for (int i=0;i<4;i++) pr[i] = *(const float4*)&Ps[(ty*4+i)*68 + cs*4];
#pragma unroll
            for (int m=0;m<4;m++) vv[m] = *(const float4*)&Vs[(cs*4+m)*64 + voff];
#pragma unroll
            for (int i=0;i<4;i++){
                o[i][0] = fmaf(pr[i].x, vv[0].x, o[i][0]);
                o[i][1] = fmaf(pr[i].x, vv[0].y, o[i][1]);
                o[i][2] = fmaf(pr[i].x, vv[0].z, o[i][2]);
                o[i][3] = fmaf(pr[i].x, vv[0].w, o[i][3]);
                o[i][0] = fmaf(pr[i].y, vv[1].x, o[i][0]);
                o[i][1] = fmaf(pr[i].y, vv[1].y, o[i][1]);
                o[i][2] = fmaf(pr[i].y, vv[1].z, o[i][2]);
                o[i][3] = fmaf(pr[i].y, vv[1].w, o[i][3]);
                o[i][0] = fmaf(pr[i].z, vv[2].x, o[i][0]);
                o[i][1] = fmaf(pr[i].z, vv[2].y, o[i][1]);
                o[i][2] = fmaf(pr[i].z, vv[2].z, o[i][2]);
                o[i][3] = fmaf(pr[i].z, vv[2].w, o[i][3]);
                o[i][0] = fmaf(pr[i].w, vv[3].x, o[i][0]);
                o[i][1] = fmaf(pr[i].w, vv[3].y, o[i][1]);
                o[i][2] = fmaf(pr[i].w, vv[3].z, o[i][2]);
                o[i][3] = fmaf(pr[i].w, vv[3].w, o[i][3]);
            }
        }
    }

#pragma unroll
    for (int i=0;i<4;i++){
        float inv = 1.0f / l_run[i];
        int t = qb*64 + ty*4 + i;
        float4 v = { o[i][0]*inv, o[i][1]*inv, o[i][2]*inv, o[i][3]*inv };
        *(float4*)(att + ((size_t)b*T_ + t)*D_ + h*HD_ + tx*4) = v;
    }
}

// ---------------------------------------------------------------------------
// Output projection: out = att @ Wo + bo.  grid (M_/128, D_/64), block 256.
// (unchanged this round)
// ---------------------------------------------------------------------------
__global__ __launch_bounds__(256) void oproj(
    const float* __restrict__ A, const float* __restrict__ Wo,
    const float* __restrict__ bo, float* __restrict__ out)
{
    const int n0  = blockIdx.y * 64;
    const int m0  = blockIdx.x * 128;
    const int tid = threadIdx.x;
    const int tx  = tid & 15, ty = tid >> 4;

    __shared__ float At[32][132];
    __shared__ float Bs[32][68];

    float acc[8][4];
#pragma unroll
    for (int i=0;i<8;i++)
#pragma unroll
      for (int j=0;j<4;j++) acc[i][j]=0.f;

    const int ar  = tid >> 1;
    const int ac0 = (tid & 1) * 16;
    const int br  = tid >> 3;
    const int bc0 = (tid & 7) * 8;

    for (int k0 = 0; k0 < D_; k0 += 32) {
        const float* ap = A + (size_t)(m0 + ar) * D_ + k0 + ac0;
        float4 a0 = *(const float4*)(ap + 0);
        float4 a1 = *(const float4*)(ap + 4);
        float4 a2 = *(const float4*)(ap + 8);
        float4 a3 = *(const float4*)(ap + 12);
        const float* wp = Wo + (size_t)(k0 + br) * D_ + n0 + bc0;
        float4 b0 = *(const float4*)(wp + 0);
        float4 b1 = *(const float4*)(wp + 4);
        __syncthreads();
        At[ac0+ 0][ar]=a0.x; At[ac0+ 1][ar]=a0.y; At[ac0+ 2][ar]=a0.z; At[ac0+ 3][ar]=a0.w;
        At[ac0+ 4][ar]=a1.x; At[ac0+ 5][ar]=a1.y; At[ac0+ 6][ar]=a1.z; At[ac0+ 7][ar]=a1.w;
        At[ac0+ 8][ar]=a2.x; At[ac0+ 9][ar]=a2.y; At[ac0+10][ar]=a2.z; At[ac0+11][ar]=a2.w;
        At[ac0+12][ar]=a3.x; At[ac0+13][ar]=a3.y; At[ac0+14][ar]=a3.z; At[ac0+15][ar]=a3.w;
        *(float4*)&Bs[br][bc0]   = b0;
        *(float4*)&Bs[br][bc0+4] = b1;
        __syncthreads();
#pragma unroll
        for (int k=0;k<32;k++){
            float4 qa0 = *(const float4*)&At[k][ty*8];
            float4 qa1 = *(const float4*)&At[k][ty*8+4];
            float4 qb  = *(const float4*)&Bs[k][tx*4];
            float aa[8]={qa0.x,qa0.y,qa0.z,qa0.w,qa1.x,qa1.y,qa1.z,qa1.w};
            float bb[4]={qb.x,qb.y,qb.z,qb.w};
#pragma unroll
            for (int i=0;i<8;i++)
#pragma unroll
                for (int j=0;j<4;j++)
                    acc[i][j] = fmaf(aa[i], bb[j], acc[i][j]);
        }
    }
    float bj[4];
#pragma unroll
    for (int j=0;j<4;j++) bj[j] = bo[n0 + tx*4 + j];
#pragma unroll
    for (int i=0;i<8;i++){
        int m = m0 + ty*8 + i;
        float4 v;
        v.x = acc[i][0]+bj[0];
        v.y = acc[i][1]+bj[1];
        v.z = acc[i][2]+bj[2];
        v.w = acc[i][3]+bj[3];
        *(float4*)(out + (size_t)m*D_ + n0 + tx*4) = v;
    }
}

extern "C" void kernel_launch(void* const* d_in, const int* in_sizes, int n_in,
                              void* d_out, int out_size, void* d_ws, size_t ws_size,
                              hipStream_t stream)
{
    const float* x  = (const float*)d_in[0];
    const float* Wq = (const float*)d_in[1];
    const float* bq = (const float*)d_in[2];
    const float* Wk = (const float*)d_in[3];
    const float* bk = (const float*)d_in[4];
    const float* Wv = (const float*)d_in[5];
    const float* bv = (const float*)d_in[6];
    const float* Wo = (const float*)d_in[7];
    const float* bo = (const float*)d_in[8];
    const int* mask = (const int*)d_in[9];
    float* out = (float*)d_out;

    float* qws = (float*)d_ws;                       // [B,H,T,HD] 32MB (q*8)
    float* kws = qws + (size_t)8*1024*1024;          // 32MB
    float* vws = kws + (size_t)8*1024*1024;          // 32MB
    float* att = vws + (size_t)8*1024*1024;          // [B,T,D] 32MB

    qkv_proj<<<dim3(M_/128, H_, 3), 256, 0, stream>>>(x, Wq, bq, Wk, bk, Wv, bv,
                                                      qws, kws, vws);
    attn<<<dim3(2048), 256, 0, stream>>>(qws, kws, vws, att, mask);
    oproj<<<dim3(M_/128, D_/64), 256, 0, stream>>>(att, Wo, bo, out);
}

// Round 6
// 1334.871 us; speedup vs baseline: 1.6594x; 1.1610x over previous
//
#include <hip/hip_runtime.h>
#include <hip/hip_bf16.h>
#include <math.h>

#define B_  4
#define T_  2048
#define D_  1024
#define H_  16
#define HD_ 64
#define M_  8192   // B_*T_

// ---------------------------------------------------------------------------
// QKV projection: out[b,h,t,e] = (sum_d x[b,t,d]*W[h,d,e] + bias[h,e]) * scl
// scl = 8 (= sqrt(64), the reference's score scale) folded into q only.
// grid (M_/128, H_, 3), block 256 (16x16), thread tile 8x4, K-chunk 32.
// (unchanged this round)
// ---------------------------------------------------------------------------
__global__ __launch_bounds__(256) void qkv_proj(
    const float* __restrict__ x,
    const float* __restrict__ Wq, const float* __restrict__ bq,
    const float* __restrict__ Wk, const float* __restrict__ bk,
    const float* __restrict__ Wv, const float* __restrict__ bv,
    float* __restrict__ qws, float* __restrict__ kws, float* __restrict__ vws)
{
    const int z = blockIdx.z;
    const float* W    = (z==0) ? Wq : (z==1) ? Wk : Wv;
    const float* bias = (z==0) ? bq : (z==1) ? bk : bv;
    float*       out  = (z==0) ? qws : (z==1) ? kws : vws;
    const int h   = blockIdx.y;
    const int m0  = blockIdx.x * 128;
    const int tid = threadIdx.x;
    const int tx  = tid & 15, ty = tid >> 4;

    __shared__ float At[32][132];  // [k][m] transposed A tile
    __shared__ float Bs[32][68];   // [k][n]

    float acc[8][4];
#pragma unroll
    for (int i=0;i<8;i++)
#pragma unroll
      for (int j=0;j<4;j++) acc[i][j]=0.f;

    const int ar  = tid >> 1;        // 0..127 row in tile
    const int ac0 = (tid & 1) * 16;  // k-col base
    const int br  = tid >> 3;        // 0..31 k-row
    const int bc0 = (tid & 7) * 8;   // n-col base

    const float* Wh = W + (size_t)h * D_ * HD_;

    for (int k0 = 0; k0 < D_; k0 += 32) {
        const float* xp = x + (size_t)(m0 + ar) * D_ + k0 + ac0;
        float4 a0 = *(const float4*)(xp + 0);
        float4 a1 = *(const float4*)(xp + 4);
        float4 a2 = *(const float4*)(xp + 8);
        float4 a3 = *(const float4*)(xp + 12);
        const float* wp = Wh + (size_t)(k0 + br) * HD_ + bc0;
        float4 b0 = *(const float4*)(wp + 0);
        float4 b1 = *(const float4*)(wp + 4);
        __syncthreads();  // previous chunk's compute done before overwrite
        At[ac0+ 0][ar]=a0.x; At[ac0+ 1][ar]=a0.y; At[ac0+ 2][ar]=a0.z; At[ac0+ 3][ar]=a0.w;
        At[ac0+ 4][ar]=a1.x; At[ac0+ 5][ar]=a1.y; At[ac0+ 6][ar]=a1.z; At[ac0+ 7][ar]=a1.w;
        At[ac0+ 8][ar]=a2.x; At[ac0+ 9][ar]=a2.y; At[ac0+10][ar]=a2.z; At[ac0+11][ar]=a2.w;
        At[ac0+12][ar]=a3.x; At[ac0+13][ar]=a3.y; At[ac0+14][ar]=a3.z; At[ac0+15][ar]=a3.w;
        *(float4*)&Bs[br][bc0]   = b0;
        *(float4*)&Bs[br][bc0+4] = b1;
        __syncthreads();
#pragma unroll
        for (int k=0;k<32;k++){
            float4 qa0 = *(const float4*)&At[k][ty*8];
            float4 qa1 = *(const float4*)&At[k][ty*8+4];
            float4 qb  = *(const float4*)&Bs[k][tx*4];
            float aa[8]={qa0.x,qa0.y,qa0.z,qa0.w,qa1.x,qa1.y,qa1.z,qa1.w};
            float bb[4]={qb.x,qb.y,qb.z,qb.w};
#pragma unroll
            for (int i=0;i<8;i++)
#pragma unroll
                for (int j=0;j<4;j++)
                    acc[i][j] = fmaf(aa[i], bb[j], acc[i][j]);
        }
    }
    const float scale = (z==0) ? 8.0f : 1.0f;
    float bj[4];
#pragma unroll
    for (int j=0;j<4;j++) bj[j] = bias[h*HD_ + tx*4 + j];
#pragma unroll
    for (int i=0;i<8;i++){
        int m = m0 + ty*8 + i;
        int b = m >> 11, t = m & (T_-1);
        float4 v;
        v.x = (acc[i][0]+bj[0])*scale;
        v.y = (acc[i][1]+bj[1])*scale;
        v.z = (acc[i][2]+bj[2])*scale;
        v.w = (acc[i][3]+bj[3])*scale;
        *(float4*)(out + ((size_t)(b*H_ + h)*T_ + t)*HD_ + tx*4) = v;
    }
}

// ---------------------------------------------------------------------------
// Flash attention (fp32), conflict-free LDS, 48KB/block -> 3 blocks/CU.
// All three tiles 64x64, XOR-swizzled float4 blocks: phys = c ^ (row>>2).
// P reuses KS after QK^T (K dead); extra barrier pair around P write.
// grid 2048 (big qb first); block 256 (16x16), 4x4/thread.
// ---------------------------------------------------------------------------
__global__ __launch_bounds__(256) void attn(
    const float* __restrict__ qws, const float* __restrict__ kws,
    const float* __restrict__ vws, float* __restrict__ att,
    const int* __restrict__ maskp)
{
    const int bid = blockIdx.x;
    const int qb  = 31 - (bid >> 6);   // big blocks first (load balance)
    const int bh  = bid & 63;
    const int b   = bh >> 4, h = bh & 15;
    const int tid = threadIdx.x;
    const int tx  = tid & 15, ty = tid >> 4;
    const int domask = maskp[0];

    __shared__ __align__(16) float KS[64*64];   // K tile, then P tile (swizzled)
    __shared__ __align__(16) float Vs[64*64];   // V tile (swizzled, row-major)
    __shared__ __align__(16) float Qs[64*64];   // Q tile (swizzled)

    const float* qp = qws + ((size_t)bh*T_ + qb*64)*HD_;
    const float* kp = kws + (size_t)bh*T_*HD_;
    const float* vp = vws + (size_t)bh*T_*HD_;

    const int r  = tid >> 2;          // 0..63 staging row
    const int q4 = (tid & 3) * 4;     // staging logical block base
    const int fr = r >> 2;            // swizzle key for staging row

    {   // load Q tile (swizzled; visible after first in-loop barrier pair)
        const float* src = qp + r*HD_ + q4*4;
        float4 v0=*(const float4*)(src+0), v1=*(const float4*)(src+4);
        float4 v2=*(const float4*)(src+8), v3=*(const float4*)(src+12);
        *(float4*)&Qs[r*64 + 4*((q4+0)^fr)] = v0;
        *(float4*)&Qs[r*64 + 4*((q4+1)^fr)] = v1;
        *(float4*)&Qs[r*64 + 4*((q4+2)^fr)] = v2;
        *(float4*)&Qs[r*64 + 4*((q4+3)^fr)] = v3;
    }

    float o[4][4];
    float m_run[4], l_run[4];
#pragma unroll
    for (int i=0;i<4;i++){
        m_run[i] = -INFINITY; l_run[i] = 0.f;
#pragma unroll
        for (int j=0;j<4;j++) o[i][j] = 0.f;
    }

    const int kv_end = domask ? qb : 31;
    for (int kv = 0; kv <= kv_end; ++kv){
        const float* ksrc = kp + (size_t)(kv*64+r)*HD_ + q4*4;
        float4 k0=*(const float4*)(ksrc+0), k1=*(const float4*)(ksrc+4);
        float4 k2=*(const float4*)(ksrc+8), k3=*(const float4*)(ksrc+12);
        const float* vsrc = vp + (size_t)(kv*64+r)*HD_ + q4*4;
        float4 w0=*(const float4*)(vsrc+0), w1=*(const float4*)(vsrc+4);
        float4 w2=*(const float4*)(vsrc+8), w3=*(const float4*)(vsrc+12);
        __syncthreads();  // prev tile's PV reads of KS(P) + Vs complete
        *(float4*)&KS[r*64 + 4*((q4+0)^fr)] = k0;
        *(float4*)&KS[r*64 + 4*((q4+1)^fr)] = k1;
        *(float4*)&KS[r*64 + 4*((q4+2)^fr)] = k2;
        *(float4*)&KS[r*64 + 4*((q4+3)^fr)] = k3;
        *(float4*)&Vs[r*64 + 4*((q4+0)^fr)] = w0;
        *(float4*)&Vs[r*64 + 4*((q4+1)^fr)] = w1;
        *(float4*)&Vs[r*64 + 4*((q4+2)^fr)] = w2;
        *(float4*)&Vs[r*64 + 4*((q4+3)^fr)] = w3;
        __syncthreads();

        // S = Q K^T (4x4/thread). K phys block (e>>2)^tx; Q phys block (e>>2)^ty.
        float s[4][4];
#pragma unroll
        for (int i=0;i<4;i++)
#pragma unroll
            for (int j=0;j<4;j++) s[i][j]=0.f;
#pragma unroll
        for (int e=0;e<64;e+=4){
            const int koff = 4*((e>>2) ^ tx);
            const int qoff = 4*((e>>2) ^ ty);
            float4 qv[4], kv4[4];
#pragma unroll
            for (int i=0;i<4;i++) qv[i]  = *(const float4*)&Qs[(ty*4+i)*64 + qoff];
#pragma unroll
            for (int j=0;j<4;j++) kv4[j] = *(const float4*)&KS[(tx*4+j)*64 + koff];
#pragma unroll
            for (int i=0;i<4;i++)
#pragma unroll
                for (int j=0;j<4;j++){
                    s[i][j] = fmaf(qv[i].x, kv4[j].x, s[i][j]);
                    s[i][j] = fmaf(qv[i].y, kv4[j].y, s[i][j]);
                    s[i][j] = fmaf(qv[i].z, kv4[j].z, s[i][j]);
                    s[i][j] = fmaf(qv[i].w, kv4[j].w, s[i][j]);
                }
        }
        if (domask && kv == qb){
#pragma unroll
            for (int i=0;i<4;i++)
#pragma unroll
                for (int j=0;j<4;j++)
                    if (tx*4+j > ty*4+i) s[i][j] = -INFINITY;
        }

        // online softmax (16-lane row groups; xor masks stay in-group)
        float p[4][4];
#pragma unroll
        for (int i=0;i<4;i++){
            float mloc = fmaxf(fmaxf(s[i][0],s[i][1]), fmaxf(s[i][2],s[i][3]));
            mloc = fmaxf(mloc, __shfl_xor(mloc,1));
            mloc = fmaxf(mloc, __shfl_xor(mloc,2));
            mloc = fmaxf(mloc, __shfl_xor(mloc,4));
            mloc = fmaxf(mloc, __shfl_xor(mloc,8));
            float mnew = fmaxf(m_run[i], mloc);
            float scl  = __expf(m_run[i] - mnew);  // exp(-inf)=0 on first tile
            m_run[i] = mnew;
            float rs = 0.f;
#pragma unroll
            for (int j=0;j<4;j++){ p[i][j] = __expf(s[i][j]-mnew); rs += p[i][j]; }
            rs += __shfl_xor(rs,1); rs += __shfl_xor(rs,2);
            rs += __shfl_xor(rs,4); rs += __shfl_xor(rs,8);
            l_run[i] = l_run[i]*scl + rs;
#pragma unroll
            for (int j=0;j<4;j++) o[i][j] *= scl;
        }
        __syncthreads();  // all QK^T reads of KS done before P overwrites K
        // P write into KS: row 4ty+i, logical block tx -> phys tx^ty
#pragma unroll
        for (int i=0;i<4;i++){
            float4 pv4 = { p[i][0], p[i][1], p[i][2], p[i][3] };
            *(float4*)&KS[(ty*4+i)*64 + 4*(tx ^ ty)] = pv4;
        }
        __syncthreads();

        // O += P V : o[i][j] += P[4ty+i][4cs+m] * V[4cs+m][4tx+j]
        // P phys block cs^ty (broadcast within ty-group); V phys block tx^cs.
#pragma unroll
        for (int cs=0; cs<16; ++cs){
            const int poff = 4*(cs ^ ty);
            const int voff = 4*(tx ^ cs);
            float4 pr[4], vv[4];
#pragma unroll
            for (int i=0;i<4;i++) pr[i] = *(const float4*)&KS[(ty*4+i)*64 + poff];
#pragma unroll
            for (int m=0;m<4;m++) vv[m] = *(const float4*)&Vs[(cs*4+m)*64 + voff];
#pragma unroll
            for (int i=0;i<4;i++){
                o[i][0] = fmaf(pr[i].x, vv[0].x, o[i][0]);
                o[i][1] = fmaf(pr[i].x, vv[0].y, o[i][1]);
                o[i][2] = fmaf(pr[i].x, vv[0].z, o[i][2]);
                o[i][3] = fmaf(pr[i].x, vv[0].w, o[i][3]);
                o[i][0] = fmaf(pr[i].y, vv[1].x, o[i][0]);
                o[i][1] = fmaf(pr[i].y, vv[1].y, o[i][1]);
                o[i][2] = fmaf(pr[i].y, vv[1].z, o[i][2]);
                o[i][3] = fmaf(pr[i].y, vv[1].w, o[i][3]);
                o[i][0] = fmaf(pr[i].z, vv[2].x, o[i][0]);
                o[i][1] = fmaf(pr[i].z, vv[2].y, o[i][1]);
                o[i][2] = fmaf(pr[i].z, vv[2].z, o[i][2]);
                o[i][3] = fmaf(pr[i].z, vv[2].w, o[i][3]);
                o[i][0] = fmaf(pr[i].w, vv[3].x, o[i][0]);
                o[i][1] = fmaf(pr[i].w, vv[3].y, o[i][1]);
                o[i][2] = fmaf(pr[i].w, vv[3].z, o[i][2]);
                o[i][3] = fmaf(pr[i].w, vv[3].w, o[i][3]);
            }
        }
    }

#pragma unroll
    for (int i=0;i<4;i++){
        float inv = 1.0f / l_run[i];
        int t = qb*64 + ty*4 + i;
        float4 v = { o[i][0]*inv, o[i][1]*inv, o[i][2]*inv, o[i][3]*inv };
        *(float4*)(att + ((size_t)b*T_ + t)*D_ + h*HD_ + tx*4) = v;
    }
}

// ---------------------------------------------------------------------------
// Output projection: out = att @ Wo + bo.  grid (M_/128, D_/64), block 256.
// (unchanged this round)
// ---------------------------------------------------------------------------
__global__ __launch_bounds__(256) void oproj(
    const float* __restrict__ A, const float* __restrict__ Wo,
    const float* __restrict__ bo, float* __restrict__ out)
{
    const int n0  = blockIdx.y * 64;
    const int m0  = blockIdx.x * 128;
    const int tid = threadIdx.x;
    const int tx  = tid & 15, ty = tid >> 4;

    __shared__ float At[32][132];
    __shared__ float Bs[32][68];

    float acc[8][4];
#pragma unroll
    for (int i=0;i<8;i++)
#pragma unroll
      for (int j=0;j<4;j++) acc[i][j]=0.f;

    const int ar  = tid >> 1;
    const int ac0 = (tid & 1) * 16;
    const int br  = tid >> 3;
    const int bc0 = (tid & 7) * 8;

    for (int k0 = 0; k0 < D_; k0 += 32) {
        const float* ap = A + (size_t)(m0 + ar) * D_ + k0 + ac0;
        float4 a0 = *(const float4*)(ap + 0);
        float4 a1 = *(const float4*)(ap + 4);
        float4 a2 = *(const float4*)(ap + 8);
        float4 a3 = *(const float4*)(ap + 12);
        const float* wp = Wo + (size_t)(k0 + br) * D_ + n0 + bc0;
        float4 b0 = *(const float4*)(wp + 0);
        float4 b1 = *(const float4*)(wp + 4);
        __syncthreads();
        At[ac0+ 0][ar]=a0.x; At[ac0+ 1][ar]=a0.y; At[ac0+ 2][ar]=a0.z; At[ac0+ 3][ar]=a0.w;
        At[ac0+ 4][ar]=a1.x; At[ac0+ 5][ar]=a1.y; At[ac0+ 6][ar]=a1.z; At[ac0+ 7][ar]=a1.w;
        At[ac0+ 8][ar]=a2.x; At[ac0+ 9][ar]=a2.y; At[ac0+10][ar]=a2.z; At[ac0+11][ar]=a2.w;
        At[ac0+12][ar]=a3.x; At[ac0+13][ar]=a3.y; At[ac0+14][ar]=a3.z; At[ac0+15][ar]=a3.w;
        *(float4*)&Bs[br][bc0]   = b0;
        *(float4*)&Bs[br][bc0+4] = b1;
        __syncthreads();
#pragma unroll
        for (int k=0;k<32;k++){
            float4 qa0 = *(const float4*)&At[k][ty*8];
            float4 qa1 = *(const float4*)&At[k][ty*8+4];
            float4 qb  = *(const float4*)&Bs[k][tx*4];
            float aa[8]={qa0.x,qa0.y,qa0.z,qa0.w,qa1.x,qa1.y,qa1.z,qa1.w};
            float bb[4]={qb.x,qb.y,qb.z,qb.w};
#pragma unroll
            for (int i=0;i<8;i++)
#pragma unroll
                for (int j=0;j<4;j++)
                    acc[i][j] = fmaf(aa[i], bb[j], acc[i][j]);
        }
    }
    float bj[4];
#pragma unroll
    for (int j=0;j<4;j++) bj[j] = bo[n0 + tx*4 + j];
#pragma unroll
    for (int i=0;i<8;i++){
        int m = m0 + ty*8 + i;
        float4 v;
        v.x = acc[i][0]+bj[0];
        v.y = acc[i][1]+bj[1];
        v.z = acc[i][2]+bj[2];
        v.w = acc[i][3]+bj[3];
        *(float4*)(out + (size_t)m*D_ + n0 + tx*4) = v;
    }
}

extern "C" void kernel_launch(void* const* d_in, const int* in_sizes, int n_in,
                              void* d_out, int out_size, void* d_ws, size_t ws_size,
                              hipStream_t stream)
{
    const float* x  = (const float*)d_in[0];
    const float* Wq = (const float*)d_in[1];
    const float* bq = (const float*)d_in[2];
    const float* Wk = (const float*)d_in[3];
    const float* bk = (const float*)d_in[4];
    const float* Wv = (const float*)d_in[5];
    const float* bv = (const float*)d_in[6];
    const float* Wo = (const float*)d_in[7];
    const float* bo = (const float*)d_in[8];
    const int* mask = (const int*)d_in[9];
    float* out = (float*)d_out;

    float* qws = (float*)d_ws;                       // [B,H,T,HD] 32MB (q*8)
    float* kws = qws + (size_t)8*1024*1024;          // 32MB
    float* vws = kws + (size_t)8*1024*1024;          // 32MB
    float* att = vws + (size_t)8*1024*1024;          // [B,T,D] 32MB

    qkv_proj<<<dim3(M_/128, H_, 3), 256, 0, stream>>>(x, Wq, bq, Wk, bk, Wv, bv,
                                                      qws, kws, vws);
    attn<<<dim3(2048), 256, 0, stream>>>(qws, kws, vws, att, mask);
    oproj<<<dim3(M_/128, D_/64), 256, 0, stream>>>(att, Wo, bo, out);
}

// Round 8
// 998.450 us; speedup vs baseline: 2.2185x; 1.3369x over previous
//
#include <hip/hip_runtime.h>
#include <hip/hip_bf16.h>
#include <math.h>

#define B_  4
#define T_  2048
#define D_  1024
#define H_  16
#define HD_ 64
#define M_  8192   // B_*T_

typedef __attribute__((ext_vector_type(8))) short bf16x8;
typedef __attribute__((ext_vector_type(4))) float f32x4;

static __device__ __forceinline__ unsigned short f2bf(float f){
    unsigned int u = __float_as_uint(f);
    unsigned int r = u + 0x7FFFu + ((u >> 16) & 1u);   // RNE
    return (unsigned short)(r >> 16);
}
static __device__ __forceinline__ float bfbits2f(unsigned short s){
    return __uint_as_float(((unsigned int)s) << 16);
}
static __device__ __forceinline__ float bf2f_lo(unsigned int u){ return __uint_as_float(u << 16); }
static __device__ __forceinline__ float bf2f_hi(unsigned int u){ return __uint_as_float(u & 0xFFFF0000u); }

union U16x16 { unsigned short us[16]; uint4 q[2]; };
union U16x4  { unsigned short us[4];  uint2 q;    };

// ---------------------------------------------------------------------------
// prep_x2: x fp32 -> xh (bf16 hi) + xl (bf16 residual). 16 el/thread.
// ---------------------------------------------------------------------------
__global__ __launch_bounds__(256) void prep_x2(
    const float* __restrict__ x,
    unsigned short* __restrict__ xh, unsigned short* __restrict__ xl)
{
    const size_t i = ((size_t)blockIdx.x*256 + threadIdx.x)*16;
    U16x16 uh, ul;
#pragma unroll
    for (int j=0;j<16;j+=4){
        float4 f = *(const float4*)(x+i+j);
        float v[4] = {f.x,f.y,f.z,f.w};
#pragma unroll
        for (int k=0;k<4;k++){
            unsigned short hb = f2bf(v[k]);
            uh.us[j+k] = hb;
            ul.us[j+k] = f2bf(v[k] - bfbits2f(hb));
        }
    }
    *(uint4*)(xh+i)   = uh.q[0]; *(uint4*)(xh+i+8) = uh.q[1];
    *(uint4*)(xl+i)   = ul.q[0]; *(uint4*)(xl+i+8) = ul.q[1];
}

// ---------------------------------------------------------------------------
// prep_wqkv2: W{q,k,v}[16][1024][64] -> wt_hi/wt_lo[3072][1024] (operand-major).
// ---------------------------------------------------------------------------
__global__ __launch_bounds__(256) void prep_wqkv2(
    const float* __restrict__ Wq, const float* __restrict__ Wk,
    const float* __restrict__ Wv,
    unsigned short* __restrict__ wh, unsigned short* __restrict__ wl)
{
    const int dt = blockIdx.x;
    const int zh = blockIdx.y;
    const int z = zh >> 4, h = zh & 15;
    const float* src = ((z==0)?Wq:(z==1)?Wk:Wv) + (size_t)h*1024*64;
    __shared__ float Tt[64][68];
    const int t = threadIdx.x;
    const int r = t >> 2, c4 = (t & 3) * 16;
    const float* sp = src + (size_t)(dt*64 + r)*64 + c4;
    float4 v0=*(const float4*)(sp+0), v1=*(const float4*)(sp+4);
    float4 v2=*(const float4*)(sp+8), v3=*(const float4*)(sp+12);
    *(float4*)&Tt[r][c4+ 0]=v0; *(float4*)&Tt[r][c4+ 4]=v1;
    *(float4*)&Tt[r][c4+ 8]=v2; *(float4*)&Tt[r][c4+12]=v3;
    __syncthreads();
    const int er = t >> 2, dk = (t & 3) * 16;
    U16x16 uh, ul;
#pragma unroll
    for (int j=0;j<16;j++){
        float v = Tt[dk+j][er];
        unsigned short hb = f2bf(v);
        uh.us[j] = hb;
        ul.us[j] = f2bf(v - bfbits2f(hb));
    }
    size_t off = (size_t)(z*1024 + h*64 + er)*1024 + dt*64 + dk;
    *(uint4*)(wh+off)   = uh.q[0]; *(uint4*)(wh+off+8) = uh.q[1];
    *(uint4*)(wl+off)   = ul.q[0]; *(uint4*)(wl+off+8) = ul.q[1];
}

// ---------------------------------------------------------------------------
// prep_wo: Wo[1024][1024] -> wot[n][k] bf16 (hi only).
// ---------------------------------------------------------------------------
__global__ __launch_bounds__(256) void prep_wo(
    const float* __restrict__ Wo, unsigned short* __restrict__ wot)
{
    const int kt = blockIdx.x, nt = blockIdx.y;
    __shared__ float Tt[64][68];
    const int t = threadIdx.x;
    const int r = t >> 2, c4 = (t & 3) * 16;
    const float* sp = Wo + (size_t)(kt*64 + r)*1024 + nt*64 + c4;
    float4 v0=*(const float4*)(sp+0), v1=*(const float4*)(sp+4);
    float4 v2=*(const float4*)(sp+8), v3=*(const float4*)(sp+12);
    *(float4*)&Tt[r][c4+ 0]=v0; *(float4*)&Tt[r][c4+ 4]=v1;
    *(float4*)&Tt[r][c4+ 8]=v2; *(float4*)&Tt[r][c4+12]=v3;
    __syncthreads();
    const int er = t >> 2, dk = (t & 3) * 16;
    U16x16 u;
#pragma unroll
    for (int j=0;j<16;j++) u.us[j] = f2bf(Tt[dk+j][er]);
    unsigned short* dst = wot + (size_t)(nt*64 + er)*1024 + kt*64 + dk;
    *(uint4*)(dst)   = u.q[0];
    *(uint4*)(dst+8) = u.q[1];
}

#define KPAD 40

// ---------------------------------------------------------------------------
// gemm_qkv3: C[128x128]/block, 4 waves, 64x64/wave, bf16 16x16x32 MFMA.
// Split-precision (hi*hi + hi*lo + lo*hi) for q,k blocks (n0<2048);
// single bf16 product for v blocks; v written bf16.
// ---------------------------------------------------------------------------
__global__ __launch_bounds__(256) void gemm_qkv3(
    const unsigned short* __restrict__ xh, const unsigned short* __restrict__ xl,
    const unsigned short* __restrict__ wh, const unsigned short* __restrict__ wl,
    const float* __restrict__ bqv, const float* __restrict__ bkv,
    const float* __restrict__ bvv,
    float* __restrict__ qws, float* __restrict__ kws,
    unsigned short* __restrict__ vb)
{
    const int m0 = blockIdx.x * 128;
    const int n0 = blockIdx.y * 128;
    const bool precise = (n0 < 2048);   // q,k need split precision
    const int tid = threadIdx.x;
    const int lane = tid & 63, wid = tid >> 6;
    const int wr = wid >> 1, wc = wid & 1;
    const int fla = lane & 15, flb = lane >> 4;

    __shared__ unsigned short Ah[128*KPAD];
    __shared__ unsigned short Al[128*KPAD];
    __shared__ unsigned short Bh[128*KPAD];
    __shared__ unsigned short Bl[128*KPAD];

    f32x4 acc[4][4];
#pragma unroll
    for (int i=0;i<4;i++)
#pragma unroll
        for (int j=0;j<4;j++) acc[i][j] = (f32x4){0.f,0.f,0.f,0.f};

    const int sr = tid >> 1, sh = tid & 1;
    const size_t aoff = (size_t)(m0+sr)*1024 + sh*16;
    const size_t boff = (size_t)(n0+sr)*1024 + sh*16;
    unsigned short* ahd = &Ah[sr*KPAD + sh*16];
    unsigned short* ald = &Al[sr*KPAD + sh*16];
    unsigned short* bhd = &Bh[sr*KPAD + sh*16];
    unsigned short* bld = &Bl[sr*KPAD + sh*16];

    for (int ks = 0; ks < 32; ++ks){
        uint4 ah0 = *(const uint4*)(xh + aoff + ks*32);
        uint4 ah1 = *(const uint4*)(xh + aoff + ks*32 + 8);
        uint4 bh0 = *(const uint4*)(wh + boff + ks*32);
        uint4 bh1 = *(const uint4*)(wh + boff + ks*32 + 8);
        uint4 al0, al1, bl0, bl1;
        if (precise){
            al0 = *(const uint4*)(xl + aoff + ks*32);
            al1 = *(const uint4*)(xl + aoff + ks*32 + 8);
            bl0 = *(const uint4*)(wl + boff + ks*32);
            bl1 = *(const uint4*)(wl + boff + ks*32 + 8);
        }
        __syncthreads();
        *(uint4*)(ahd)   = ah0; *(uint4*)(ahd+8) = ah1;
        *(uint4*)(bhd)   = bh0; *(uint4*)(bhd+8) = bh1;
        if (precise){
            *(uint4*)(ald)   = al0; *(uint4*)(ald+8) = al1;
            *(uint4*)(bld)   = bl0; *(uint4*)(bld+8) = bl1;
        }
        __syncthreads();
        bf16x8 afh[4], bfh[4];
#pragma unroll
        for (int mf=0; mf<4; ++mf)
            afh[mf] = *(const bf16x8*)&Ah[(wr*64+mf*16+fla)*KPAD + flb*8];
#pragma unroll
        for (int nf=0; nf<4; ++nf)
            bfh[nf] = *(const bf16x8*)&Bh[(wc*64+nf*16+fla)*KPAD + flb*8];
        if (precise){
            bf16x8 afl[4], bfl[4];
#pragma unroll
            for (int mf=0; mf<4; ++mf)
                afl[mf] = *(const bf16x8*)&Al[(wr*64+mf*16+fla)*KPAD + flb*8];
#pragma unroll
            for (int nf=0; nf<4; ++nf)
                bfl[nf] = *(const bf16x8*)&Bl[(wc*64+nf*16+fla)*KPAD + flb*8];
#pragma unroll
            for (int mf=0; mf<4; ++mf)
#pragma unroll
                for (int nf=0; nf<4; ++nf){
                    acc[mf][nf] = __builtin_amdgcn_mfma_f32_16x16x32_bf16(
                                      afh[mf], bfl[nf], acc[mf][nf], 0, 0, 0);
                    acc[mf][nf] = __builtin_amdgcn_mfma_f32_16x16x32_bf16(
                                      afl[mf], bfh[nf], acc[mf][nf], 0, 0, 0);
                    acc[mf][nf] = __builtin_amdgcn_mfma_f32_16x16x32_bf16(
                                      afh[mf], bfh[nf], acc[mf][nf], 0, 0, 0);
                }
        } else {
#pragma unroll
            for (int mf=0; mf<4; ++mf)
#pragma unroll
                for (int nf=0; nf<4; ++nf)
                    acc[mf][nf] = __builtin_amdgcn_mfma_f32_16x16x32_bf16(
                                      afh[mf], bfh[nf], acc[mf][nf], 0, 0, 0);
        }
    }

    if (precise){
#pragma unroll
        for (int nf=0; nf<4; ++nf){
            const int c = n0 + wc*64 + nf*16 + fla;
            const int z = c >> 10, rem = c & 1023;
            const int h = rem >> 6, e = rem & 63;
            const float bias = ((z==0)?bqv:bkv)[rem];
            const float scl  = (z==0) ? 8.0f : 1.0f;
            float* outp = (z==0)?qws:kws;
#pragma unroll
            for (int mf=0; mf<4; ++mf){
#pragma unroll
                for (int ri=0; ri<4; ++ri){
                    const int m = m0 + wr*64 + mf*16 + flb*4 + ri;
                    const int b = m >> 11, t = m & (T_-1);
                    outp[((size_t)(b*H_ + h)*T_ + t)*HD_ + e] =
                        (acc[mf][nf][ri] + bias) * scl;
                }
            }
        }
    } else {
#pragma unroll
        for (int nf=0; nf<4; ++nf){
            const int c = n0 + wc*64 + nf*16 + fla;
            const int rem = c & 1023;
            const int h = rem >> 6, e = rem & 63;
            const float bias = bvv[rem];
#pragma unroll
            for (int mf=0; mf<4; ++mf){
#pragma unroll
                for (int ri=0; ri<4; ++ri){
                    const int m = m0 + wr*64 + mf*16 + flb*4 + ri;
                    const int b = m >> 11, t = m & (T_-1);
                    vb[((size_t)(b*H_ + h)*T_ + t)*HD_ + e] =
                        f2bf(acc[mf][nf][ri] + bias);
                }
            }
        }
    }
}

// ---------------------------------------------------------------------------
// gemm_o: out = att(bf16) @ wot(bf16) + bo. (unchanged from round 7)
// ---------------------------------------------------------------------------
__global__ __launch_bounds__(256) void gemm_o(
    const unsigned short* __restrict__ attb, const unsigned short* __restrict__ wot,
    const float* __restrict__ bo, float* __restrict__ out)
{
    const int m0 = blockIdx.x * 128;
    const int n0 = blockIdx.y * 128;
    const int tid = threadIdx.x;
    const int lane = tid & 63, wid = tid >> 6;
    const int wr = wid >> 1, wc = wid & 1;
    const int fla = lane & 15, flb = lane >> 4;

    __shared__ unsigned short As[128*KPAD];
    __shared__ unsigned short Bs[128*KPAD];

    f32x4 acc[4][4];
#pragma unroll
    for (int i=0;i<4;i++)
#pragma unroll
        for (int j=0;j<4;j++) acc[i][j] = (f32x4){0.f,0.f,0.f,0.f};

    const int sr = tid >> 1, sh = tid & 1;
    const unsigned short* ap = attb + (size_t)(m0+sr)*1024 + sh*16;
    const unsigned short* bp = wot  + (size_t)(n0+sr)*1024 + sh*16;
    unsigned short* asd = &As[sr*KPAD + sh*16];
    unsigned short* bsd = &Bs[sr*KPAD + sh*16];

    for (int ks = 0; ks < 32; ++ks){
        uint4 a0 = *(const uint4*)(ap + ks*32);
        uint4 a1 = *(const uint4*)(ap + ks*32 + 8);
        uint4 b0 = *(const uint4*)(bp + ks*32);
        uint4 b1 = *(const uint4*)(bp + ks*32 + 8);
        __syncthreads();
        *(uint4*)(asd)   = a0; *(uint4*)(asd+8) = a1;
        *(uint4*)(bsd)   = b0; *(uint4*)(bsd+8) = b1;
        __syncthreads();
        bf16x8 af[4], bfr[4];
#pragma unroll
        for (int mf=0; mf<4; ++mf)
            af[mf] = *(const bf16x8*)&As[(wr*64+mf*16+fla)*KPAD + flb*8];
#pragma unroll
        for (int nf=0; nf<4; ++nf)
            bfr[nf] = *(const bf16x8*)&Bs[(wc*64+nf*16+fla)*KPAD + flb*8];
#pragma unroll
        for (int mf=0; mf<4; ++mf)
#pragma unroll
            for (int nf=0; nf<4; ++nf)
                acc[mf][nf] = __builtin_amdgcn_mfma_f32_16x16x32_bf16(
                                  af[mf], bfr[nf], acc[mf][nf], 0, 0, 0);
    }

#pragma unroll
    for (int nf=0; nf<4; ++nf){
        const int n = n0 + wc*64 + nf*16 + fla;
        const float bias = bo[n];
#pragma unroll
        for (int mf=0; mf<4; ++mf){
#pragma unroll
            for (int ri=0; ri<4; ++ri){
                const int m = m0 + wr*64 + mf*16 + flb*4 + ri;
                out[(size_t)m*D_ + n] = acc[mf][nf][ri] + bias;
            }
        }
    }
}

// ---------------------------------------------------------------------------
// Flash attention (fp32 math), conflict-free swizzled LDS, 48KB/block.
// V input bf16 (converted during staging); att output bf16.
// ---------------------------------------------------------------------------
__global__ __launch_bounds__(256) void attn(
    const float* __restrict__ qws, const float* __restrict__ kws,
    const unsigned short* __restrict__ vb, unsigned short* __restrict__ attb,
    const int* __restrict__ maskp)
{
    const int bid = blockIdx.x;
    const int qb  = 31 - (bid >> 6);
    const int bh  = bid & 63;
    const int b   = bh >> 4, h = bh & 15;
    const int tid = threadIdx.x;
    const int tx  = tid & 15, ty = tid >> 4;
    const int domask = maskp[0];

    __shared__ __align__(16) float KS[64*64];
    __shared__ __align__(16) float Vs[64*64];
    __shared__ __align__(16) float Qs[64*64];

    const float* qp = qws + ((size_t)bh*T_ + qb*64)*HD_;
    const float* kp = kws + (size_t)bh*T_*HD_;
    const unsigned short* vp = vb + (size_t)bh*T_*HD_;

    const int r  = tid >> 2;
    const int q4 = (tid & 3) * 4;
    const int fr = r >> 2;

    {
        const float* src = qp + r*HD_ + q4*4;
        float4 v0=*(const float4*)(src+0), v1=*(const float4*)(src+4);
        float4 v2=*(const float4*)(src+8), v3=*(const float4*)(src+12);
        *(float4*)&Qs[r*64 + 4*((q4+0)^fr)] = v0;
        *(float4*)&Qs[r*64 + 4*((q4+1)^fr)] = v1;
        *(float4*)&Qs[r*64 + 4*((q4+2)^fr)] = v2;
        *(float4*)&Qs[r*64 + 4*((q4+3)^fr)] = v3;
    }

    float o[4][4];
    float m_run[4], l_run[4];
#pragma unroll
    for (int i=0;i<4;i++){
        m_run[i] = -INFINITY; l_run[i] = 0.f;
#pragma unroll
        for (int j=0;j<4;j++) o[i][j] = 0.f;
    }

    const int kv_end = domask ? qb : 31;
    for (int kv = 0; kv <= kv_end; ++kv){
        const float* ksrc = kp + (size_t)(kv*64+r)*HD_ + q4*4;
        float4 k0=*(const float4*)(ksrc+0), k1=*(const float4*)(ksrc+4);
        float4 k2=*(const float4*)(ksrc+8), k3=*(const float4*)(ksrc+12);
        const unsigned short* vsrc = vp + (size_t)(kv*64+r)*HD_ + q4*4;
        uint4 wv0 = *(const uint4*)(vsrc);
        uint4 wv1 = *(const uint4*)(vsrc + 8);
        float4 w0 = { bf2f_lo(wv0.x), bf2f_hi(wv0.x), bf2f_lo(wv0.y), bf2f_hi(wv0.y) };
        float4 w1 = { bf2f_lo(wv0.z), bf2f_hi(wv0.z), bf2f_lo(wv0.w), bf2f_hi(wv0.w) };
        float4 w2 = { bf2f_lo(wv1.x), bf2f_hi(wv1.x), bf2f_lo(wv1.y), bf2f_hi(wv1.y) };
        float4 w3 = { bf2f_lo(wv1.z), bf2f_hi(wv1.z), bf2f_lo(wv1.w), bf2f_hi(wv1.w) };
        __syncthreads();
        *(float4*)&KS[r*64 + 4*((q4+0)^fr)] = k0;
        *(float4*)&KS[r*64 + 4*((q4+1)^fr)] = k1;
        *(float4*)&KS[r*64 + 4*((q4+2)^fr)] = k2;
        *(float4*)&KS[r*64 + 4*((q4+3)^fr)] = k3;
        *(float4*)&Vs[r*64 + 4*((q4+0)^fr)] = w0;
        *(float4*)&Vs[r*64 + 4*((q4+1)^fr)] = w1;
        *(float4*)&Vs[r*64 + 4*((q4+2)^fr)] = w2;
        *(float4*)&Vs[r*64 + 4*((q4+3)^fr)] = w3;
        __syncthreads();

        float s[4][4];
#pragma unroll
        for (int i=0;i<4;i++)
#pragma unroll
            for (int j=0;j<4;j++) s[i][j]=0.f;
#pragma unroll
        for (int e=0;e<64;e+=4){
            const int koff = 4*((e>>2) ^ tx);
            const int qoff = 4*((e>>2) ^ ty);
            float4 qv[4], kv4[4];
#pragma unroll
            for (int i=0;i<4;i++) qv[i]  = *(const float4*)&Qs[(ty*4+i)*64 + qoff];
#pragma unroll
            for (int j=0;j<4;j++) kv4[j] = *(const float4*)&KS[(tx*4+j)*64 + koff];
#pragma unroll
            for (int i=0;i<4;i++)
#pragma unroll
                for (int j=0;j<4;j++){
                    s[i][j] = fmaf(qv[i].x, kv4[j].x, s[i][j]);
                    s[i][j] = fmaf(qv[i].y, kv4[j].y, s[i][j]);
                    s[i][j] = fmaf(qv[i].z, kv4[j].z, s[i][j]);
                    s[i][j] = fmaf(qv[i].w, kv4[j].w, s[i][j]);
                }
        }
        if (domask && kv == qb){
#pragma unroll
            for (int i=0;i<4;i++)
#pragma unroll
                for (int j=0;j<4;j++)
                    if (tx*4+j > ty*4+i) s[i][j] = -INFINITY;
        }

        float p[4][4];
#pragma unroll
        for (int i=0;i<4;i++){
            float mloc = fmaxf(fmaxf(s[i][0],s[i][1]), fmaxf(s[i][2],s[i][3]));
            mloc = fmaxf(mloc, __shfl_xor(mloc,1));
            mloc = fmaxf(mloc, __shfl_xor(mloc,2));
            mloc = fmaxf(mloc, __shfl_xor(mloc,4));
            mloc = fmaxf(mloc, __shfl_xor(mloc,8));
            float mnew = fmaxf(m_run[i], mloc);
            float scl  = __expf(m_run[i] - mnew);
            m_run[i] = mnew;
            float rs = 0.f;
#pragma unroll
            for (int j=0;j<4;j++){ p[i][j] = __expf(s[i][j]-mnew); rs += p[i][j]; }
            rs += __shfl_xor(rs,1); rs += __shfl_xor(rs,2);
            rs += __shfl_xor(rs,4); rs += __shfl_xor(rs,8);
            l_run[i] = l_run[i]*scl + rs;
#pragma unroll
            for (int j=0;j<4;j++) o[i][j] *= scl;
        }
        __syncthreads();
#pragma unroll
        for (int i=0;i<4;i++){
            float4 pv4 = { p[i][0], p[i][1], p[i][2], p[i][3] };
            *(float4*)&KS[(ty*4+i)*64 + 4*(tx ^ ty)] = pv4;
        }
        __syncthreads();

#pragma unroll
        for (int cs=0; cs<16; ++cs){
            const int poff = 4*(cs ^ ty);
            const int voff = 4*(tx ^ cs);
            float4 pr[4], vv[4];
#pragma unroll
            for (int i=0;i<4;i++) pr[i] = *(const float4*)&KS[(ty*4+i)*64 + poff];
#pragma unroll
            for (int m=0;m<4;m++) vv[m] = *(const float4*)&Vs[(cs*4+m)*64 + voff];
#pragma unroll
            for (int i=0;i<4;i++){
                o[i][0] = fmaf(pr[i].x, vv[0].x, o[i][0]);
                o[i][1] = fmaf(pr[i].x, vv[0].y, o[i][1]);
                o[i][2] = fmaf(pr[i].x, vv[0].z, o[i][2]);
                o[i][3] = fmaf(pr[i].x, vv[0].w, o[i][3]);
                o[i][0] = fmaf(pr[i].y, vv[1].x, o[i][0]);
                o[i][1] = fmaf(pr[i].y, vv[1].y, o[i][1]);
                o[i][2] = fmaf(pr[i].y, vv[1].z, o[i][2]);
                o[i][3] = fmaf(pr[i].y, vv[1].w, o[i][3]);
                o[i][0] = fmaf(pr[i].z, vv[2].x, o[i][0]);
                o[i][1] = fmaf(pr[i].z, vv[2].y, o[i][1]);
                o[i][2] = fmaf(pr[i].z, vv[2].z, o[i][2]);
                o[i][3] = fmaf(pr[i].z, vv[2].w, o[i][3]);
                o[i][0] = fmaf(pr[i].w, vv[3].x, o[i][0]);
                o[i][1] = fmaf(pr[i].w, vv[3].y, o[i][1]);
                o[i][2] = fmaf(pr[i].w, vv[3].z, o[i][2]);
                o[i][3] = fmaf(pr[i].w, vv[3].w, o[i][3]);
            }
        }
    }

#pragma unroll
    for (int i=0;i<4;i++){
        float inv = 1.0f / l_run[i];
        int t = qb*64 + ty*4 + i;
        U16x4 u;
        u.us[0] = f2bf(o[i][0]*inv);
        u.us[1] = f2bf(o[i][1]*inv);
        u.us[2] = f2bf(o[i][2]*inv);
        u.us[3] = f2bf(o[i][3]*inv);
        *(uint2*)(attb + ((size_t)b*T_ + t)*D_ + h*HD_ + tx*4) = u.q;
    }
}

extern "C" void kernel_launch(void* const* d_in, const int* in_sizes, int n_in,
                              void* d_out, int out_size, void* d_ws, size_t ws_size,
                              hipStream_t stream)
{
    const float* x  = (const float*)d_in[0];
    const float* Wq = (const float*)d_in[1];
    const float* bq = (const float*)d_in[2];
    const float* Wk = (const float*)d_in[3];
    const float* bk = (const float*)d_in[4];
    const float* Wv = (const float*)d_in[5];
    const float* bv = (const float*)d_in[6];
    const float* Wo = (const float*)d_in[7];
    const float* bo = (const float*)d_in[8];
    const int* mask = (const int*)d_in[9];
    float* out = (float*)d_out;

    // workspace layout (126 MiB total)
    float* qws = (float*)d_ws;                                   // 32 MiB
    float* kws = qws + (size_t)8*1024*1024;                      // 32 MiB
    unsigned short* vbq  = (unsigned short*)(kws + (size_t)8*1024*1024); // 16 MiB
    unsigned short* xh   = vbq + (size_t)8*1024*1024;            // 16 MiB
    unsigned short* xl   = xh  + (size_t)8*1024*1024;            // 16 MiB
    unsigned short* wh   = xl  + (size_t)8*1024*1024;            // 6 MiB
    unsigned short* wl   = wh  + (size_t)3*1024*1024;            // 6 MiB
    unsigned short* wot  = wl  + (size_t)3*1024*1024;            // 2 MiB
    unsigned short* attb = xh;   // alias: xh dead after gemm_qkv3

    prep_x2   <<<2048, 256, 0, stream>>>(x, xh, xl);
    prep_wqkv2<<<dim3(16,48), 256, 0, stream>>>(Wq, Wk, Wv, wh, wl);
    prep_wo   <<<dim3(16,16), 256, 0, stream>>>(Wo, wot);
    gemm_qkv3 <<<dim3(64,24), 256, 0, stream>>>(xh, xl, wh, wl, bq, bk, bv,
                                                qws, kws, vbq);
    attn      <<<2048, 256, 0, stream>>>(qws, kws, vbq, attb, mask);
    gemm_o    <<<dim3(64,8), 256, 0, stream>>>(attb, wot, bo, out);
}

// Round 9
// 329.384 us; speedup vs baseline: 6.7250x; 3.0313x over previous
//
#include <hip/hip_runtime.h>
#include <hip/hip_bf16.h>
#include <math.h>

#define B_  4
#define T_  2048
#define D_  1024
#define H_  16
#define HD_ 64
#define M_  8192   // B_*T_

typedef __attribute__((ext_vector_type(8))) short bf16x8;
typedef __attribute__((ext_vector_type(4))) float f32x4;

static __device__ __forceinline__ unsigned short f2bf(float f){
    unsigned int u = __float_as_uint(f);
    unsigned int r = u + 0x7FFFu + ((u >> 16) & 1u);   // RNE
    return (unsigned short)(r >> 16);
}
static __device__ __forceinline__ float bfbits2f(unsigned short s){
    return __uint_as_float(((unsigned int)s) << 16);
}

union U16x16 { unsigned short us[16]; uint4 q[2]; };

// ---------------------------------------------------------------------------
// prep_x2: x fp32 -> xh (bf16 hi) + xl (bf16 residual). 16 el/thread.
// ---------------------------------------------------------------------------
__global__ __launch_bounds__(256) void prep_x2(
    const float* __restrict__ x,
    unsigned short* __restrict__ xh, unsigned short* __restrict__ xl)
{
    const size_t i = ((size_t)blockIdx.x*256 + threadIdx.x)*16;
    U16x16 uh, ul;
#pragma unroll
    for (int j=0;j<16;j+=4){
        float4 f = *(const float4*)(x+i+j);
        float v[4] = {f.x,f.y,f.z,f.w};
#pragma unroll
        for (int k=0;k<4;k++){
            unsigned short hb = f2bf(v[k]);
            uh.us[j+k] = hb;
            ul.us[j+k] = f2bf(v[k] - bfbits2f(hb));
        }
    }
    *(uint4*)(xh+i)   = uh.q[0]; *(uint4*)(xh+i+8) = uh.q[1];
    *(uint4*)(xl+i)   = ul.q[0]; *(uint4*)(xl+i+8) = ul.q[1];
}

// ---------------------------------------------------------------------------
// prep_wqkv2: W{q,k,v}[16][1024][64] -> wt_hi/wt_lo[3072][1024] (operand-major).
// ---------------------------------------------------------------------------
__global__ __launch_bounds__(256) void prep_wqkv2(
    const float* __restrict__ Wq, const float* __restrict__ Wk,
    const float* __restrict__ Wv,
    unsigned short* __restrict__ wh, unsigned short* __restrict__ wl)
{
    const int dt = blockIdx.x;
    const int zh = blockIdx.y;
    const int z = zh >> 4, h = zh & 15;
    const float* src = ((z==0)?Wq:(z==1)?Wk:Wv) + (size_t)h*1024*64;
    __shared__ float Tt[64][68];
    const int t = threadIdx.x;
    const int r = t >> 2, c4 = (t & 3) * 16;
    const float* sp = src + (size_t)(dt*64 + r)*64 + c4;
    float4 v0=*(const float4*)(sp+0), v1=*(const float4*)(sp+4);
    float4 v2=*(const float4*)(sp+8), v3=*(const float4*)(sp+12);
    *(float4*)&Tt[r][c4+ 0]=v0; *(float4*)&Tt[r][c4+ 4]=v1;
    *(float4*)&Tt[r][c4+ 8]=v2; *(float4*)&Tt[r][c4+12]=v3;
    __syncthreads();
    const int er = t >> 2, dk = (t & 3) * 16;
    U16x16 uh, ul;
#pragma unroll
    for (int j=0;j<16;j++){
        float v = Tt[dk+j][er];
        unsigned short hb = f2bf(v);
        uh.us[j] = hb;
        ul.us[j] = f2bf(v - bfbits2f(hb));
    }
    size_t off = (size_t)(z*1024 + h*64 + er)*1024 + dt*64 + dk;
    *(uint4*)(wh+off)   = uh.q[0]; *(uint4*)(wh+off+8) = uh.q[1];
    *(uint4*)(wl+off)   = ul.q[0]; *(uint4*)(wl+off+8) = ul.q[1];
}

// ---------------------------------------------------------------------------
// prep_wo: Wo[1024][1024] -> wot[n][k] bf16 (hi only).
// ---------------------------------------------------------------------------
__global__ __launch_bounds__(256) void prep_wo(
    const float* __restrict__ Wo, unsigned short* __restrict__ wot)
{
    const int kt = blockIdx.x, nt = blockIdx.y;
    __shared__ float Tt[64][68];
    const int t = threadIdx.x;
    const int r = t >> 2, c4 = (t & 3) * 16;
    const float* sp = Wo + (size_t)(kt*64 + r)*1024 + nt*64 + c4;
    float4 v0=*(const float4*)(sp+0), v1=*(const float4*)(sp+4);
    float4 v2=*(const float4*)(sp+8), v3=*(const float4*)(sp+12);
    *(float4*)&Tt[r][c4+ 0]=v0; *(float4*)&Tt[r][c4+ 4]=v1;
    *(float4*)&Tt[r][c4+ 8]=v2; *(float4*)&Tt[r][c4+12]=v3;
    __syncthreads();
    const int er = t >> 2, dk = (t & 3) * 16;
    U16x16 u;
#pragma unroll
    for (int j=0;j<16;j++) u.us[j] = f2bf(Tt[dk+j][er]);
    unsigned short* dst = wot + (size_t)(nt*64 + er)*1024 + kt*64 + dk;
    *(uint4*)(dst)   = u.q[0];
    *(uint4*)(dst+8) = u.q[1];
}

#define KPAD 40

// ---------------------------------------------------------------------------
// gemm_qkv3: C[128x128]/block, 4 waves, 64x64/wave, bf16 16x16x32 MFMA.
// Split-precision (hi*hi + hi*lo + lo*hi) for q,k (n0<2048), outputs split
// bf16 pairs qh/ql, kh/kl. v: single product, output bf16 TRANSPOSED [bh][d][t].
// ---------------------------------------------------------------------------
__global__ __launch_bounds__(256) void gemm_qkv3(
    const unsigned short* __restrict__ xh, const unsigned short* __restrict__ xl,
    const unsigned short* __restrict__ wh, const unsigned short* __restrict__ wl,
    const float* __restrict__ bqv, const float* __restrict__ bkv,
    const float* __restrict__ bvv,
    unsigned short* __restrict__ qhp, unsigned short* __restrict__ qlp,
    unsigned short* __restrict__ khp, unsigned short* __restrict__ klp,
    unsigned short* __restrict__ vtp)
{
    const int m0 = blockIdx.x * 128;
    const int n0 = blockIdx.y * 128;
    const bool precise = (n0 < 2048);   // q,k need split precision
    const int tid = threadIdx.x;
    const int lane = tid & 63, wid = tid >> 6;
    const int wr = wid >> 1, wc = wid & 1;
    const int fla = lane & 15, flb = lane >> 4;

    __shared__ unsigned short Ah[128*KPAD];
    __shared__ unsigned short Al[128*KPAD];
    __shared__ unsigned short Bh[128*KPAD];
    __shared__ unsigned short Bl[128*KPAD];

    f32x4 acc[4][4];
#pragma unroll
    for (int i=0;i<4;i++)
#pragma unroll
        for (int j=0;j<4;j++) acc[i][j] = (f32x4){0.f,0.f,0.f,0.f};

    const int sr = tid >> 1, sh = tid & 1;
    const size_t aoff = (size_t)(m0+sr)*1024 + sh*16;
    const size_t boff = (size_t)(n0+sr)*1024 + sh*16;
    unsigned short* ahd = &Ah[sr*KPAD + sh*16];
    unsigned short* ald = &Al[sr*KPAD + sh*16];
    unsigned short* bhd = &Bh[sr*KPAD + sh*16];
    unsigned short* bld = &Bl[sr*KPAD + sh*16];

    for (int ks = 0; ks < 32; ++ks){
        uint4 ah0 = *(const uint4*)(xh + aoff + ks*32);
        uint4 ah1 = *(const uint4*)(xh + aoff + ks*32 + 8);
        uint4 bh0 = *(const uint4*)(wh + boff + ks*32);
        uint4 bh1 = *(const uint4*)(wh + boff + ks*32 + 8);
        uint4 al0, al1, bl0, bl1;
        if (precise){
            al0 = *(const uint4*)(xl + aoff + ks*32);
            al1 = *(const uint4*)(xl + aoff + ks*32 + 8);
            bl0 = *(const uint4*)(wl + boff + ks*32);
            bl1 = *(const uint4*)(wl + boff + ks*32 + 8);
        }
        __syncthreads();
        *(uint4*)(ahd)   = ah0; *(uint4*)(ahd+8) = ah1;
        *(uint4*)(bhd)   = bh0; *(uint4*)(bhd+8) = bh1;
        if (precise){
            *(uint4*)(ald)   = al0; *(uint4*)(ald+8) = al1;
            *(uint4*)(bld)   = bl0; *(uint4*)(bld+8) = bl1;
        }
        __syncthreads();
        bf16x8 afh[4], bfh[4];
#pragma unroll
        for (int mf=0; mf<4; ++mf)
            afh[mf] = *(const bf16x8*)&Ah[(wr*64+mf*16+fla)*KPAD + flb*8];
#pragma unroll
        for (int nf=0; nf<4; ++nf)
            bfh[nf] = *(const bf16x8*)&Bh[(wc*64+nf*16+fla)*KPAD + flb*8];
        if (precise){
            bf16x8 afl[4], bfl[4];
#pragma unroll
            for (int mf=0; mf<4; ++mf)
                afl[mf] = *(const bf16x8*)&Al[(wr*64+mf*16+fla)*KPAD + flb*8];
#pragma unroll
            for (int nf=0; nf<4; ++nf)
                bfl[nf] = *(const bf16x8*)&Bl[(wc*64+nf*16+fla)*KPAD + flb*8];
#pragma unroll
            for (int mf=0; mf<4; ++mf)
#pragma unroll
                for (int nf=0; nf<4; ++nf){
                    acc[mf][nf] = __builtin_amdgcn_mfma_f32_16x16x32_bf16(
                                      afh[mf], bfl[nf], acc[mf][nf], 0, 0, 0);
                    acc[mf][nf] = __builtin_amdgcn_mfma_f32_16x16x32_bf16(
                                      afl[mf], bfh[nf], acc[mf][nf], 0, 0, 0);
                    acc[mf][nf] = __builtin_amdgcn_mfma_f32_16x16x32_bf16(
                                      afh[mf], bfh[nf], acc[mf][nf], 0, 0, 0);
                }
        } else {
#pragma unroll
            for (int mf=0; mf<4; ++mf)
#pragma unroll
                for (int nf=0; nf<4; ++nf)
                    acc[mf][nf] = __builtin_amdgcn_mfma_f32_16x16x32_bf16(
                                      afh[mf], bfh[nf], acc[mf][nf], 0, 0, 0);
        }
    }

    if (precise){
#pragma unroll
        for (int nf=0; nf<4; ++nf){
            const int c = n0 + wc*64 + nf*16 + fla;
            const int z = c >> 10, rem = c & 1023;
            const int h = rem >> 6, e = rem & 63;
            const float bias = ((z==0)?bqv:bkv)[rem];
            const float scl  = (z==0) ? 8.0f : 1.0f;
            unsigned short* oh = (z==0)?qhp:khp;
            unsigned short* ol = (z==0)?qlp:klp;
#pragma unroll
            for (int mf=0; mf<4; ++mf){
#pragma unroll
                for (int ri=0; ri<4; ++ri){
                    const int m = m0 + wr*64 + mf*16 + flb*4 + ri;
                    const int b = m >> 11, t = m & (T_-1);
                    const float val = (acc[mf][nf][ri] + bias) * scl;
                    const unsigned short hb = f2bf(val);
                    const size_t idx = ((size_t)(b*H_ + h)*T_ + t)*HD_ + e;
                    oh[idx] = hb;
                    ol[idx] = f2bf(val - bfbits2f(hb));
                }
            }
        }
    } else {
#pragma unroll
        for (int nf=0; nf<4; ++nf){
            const int c = n0 + wc*64 + nf*16 + fla;
            const int rem = c & 1023;
            const int h = rem >> 6, e = rem & 63;
            const float bias = bvv[rem];
#pragma unroll
            for (int mf=0; mf<4; ++mf){
#pragma unroll
                for (int ri=0; ri<4; ++ri){
                    const int m = m0 + wr*64 + mf*16 + flb*4 + ri;
                    const int b = m >> 11, t = m & (T_-1);
                    vtp[((size_t)(b*H_ + h)*HD_ + e)*T_ + t] =
                        f2bf(acc[mf][nf][ri] + bias);
                }
            }
        }
    }
}

// ---------------------------------------------------------------------------
// gemm_o: out = att(bf16) @ wot(bf16) + bo.
// ---------------------------------------------------------------------------
__global__ __launch_bounds__(256) void gemm_o(
    const unsigned short* __restrict__ attb, const unsigned short* __restrict__ wot,
    const float* __restrict__ bo, float* __restrict__ out)
{
    const int m0 = blockIdx.x * 128;
    const int n0 = blockIdx.y * 128;
    const int tid = threadIdx.x;
    const int lane = tid & 63, wid = tid >> 6;
    const int wr = wid >> 1, wc = wid & 1;
    const int fla = lane & 15, flb = lane >> 4;

    __shared__ unsigned short As[128*KPAD];
    __shared__ unsigned short Bs[128*KPAD];

    f32x4 acc[4][4];
#pragma unroll
    for (int i=0;i<4;i++)
#pragma unroll
        for (int j=0;j<4;j++) acc[i][j] = (f32x4){0.f,0.f,0.f,0.f};

    const int sr = tid >> 1, sh = tid & 1;
    const unsigned short* ap = attb + (size_t)(m0+sr)*1024 + sh*16;
    const unsigned short* bp = wot  + (size_t)(n0+sr)*1024 + sh*16;
    unsigned short* asd = &As[sr*KPAD + sh*16];
    unsigned short* bsd = &Bs[sr*KPAD + sh*16];

    for (int ks = 0; ks < 32; ++ks){
        uint4 a0 = *(const uint4*)(ap + ks*32);
        uint4 a1 = *(const uint4*)(ap + ks*32 + 8);
        uint4 b0 = *(const uint4*)(bp + ks*32);
        uint4 b1 = *(const uint4*)(bp + ks*32 + 8);
        __syncthreads();
        *(uint4*)(asd)   = a0; *(uint4*)(asd+8) = a1;
        *(uint4*)(bsd)   = b0; *(uint4*)(bsd+8) = b1;
        __syncthreads();
        bf16x8 af[4], bfr[4];
#pragma unroll
        for (int mf=0; mf<4; ++mf)
            af[mf] = *(const bf16x8*)&As[(wr*64+mf*16+fla)*KPAD + flb*8];
#pragma unroll
        for (int nf=0; nf<4; ++nf)
            bfr[nf] = *(const bf16x8*)&Bs[(wc*64+nf*16+fla)*KPAD + flb*8];
#pragma unroll
        for (int mf=0; mf<4; ++mf)
#pragma unroll
            for (int nf=0; nf<4; ++nf)
                acc[mf][nf] = __builtin_amdgcn_mfma_f32_16x16x32_bf16(
                                  af[mf], bfr[nf], acc[mf][nf], 0, 0, 0);
    }

#pragma unroll
    for (int nf=0; nf<4; ++nf){
        const int n = n0 + wc*64 + nf*16 + fla;
        const float bias = bo[n];
#pragma unroll
        for (int mf=0; mf<4; ++mf){
#pragma unroll
            for (int ri=0; ri<4; ++ri){
                const int m = m0 + wr*64 + mf*16 + flb*4 + ri;
                out[(size_t)m*D_ + n] = acc[mf][nf][ri] + bias;
            }
        }
    }
}

// ---------------------------------------------------------------------------
// MFMA flash attention. One block = (b,h) x 64 q-rows; 4 waves x 16 rows.
// QK^T: split bf16x3 (qh*kl + ql*kh + qh*kh) -> fp32-quality logits.
// Softmax fp32 in D-layout regs; P bf16 via wave-private LDS; PV: bf16 MFMA
// with V^T staged [d][key]. LDS 4x[64][72] bf16 = 36 KB -> 4 blocks/CU.
// ---------------------------------------------------------------------------
__global__ __launch_bounds__(256) void attn_mfma(
    const unsigned short* __restrict__ qhp, const unsigned short* __restrict__ qlp,
    const unsigned short* __restrict__ khp, const unsigned short* __restrict__ klp,
    const unsigned short* __restrict__ vtp, unsigned short* __restrict__ attb,
    const int* __restrict__ maskp)
{
    const int bid = blockIdx.x;
    const int qb  = 31 - (bid >> 6);   // big blocks first
    const int bh  = bid & 63;
    const int b   = bh >> 4, h = bh & 15;
    const int tid = threadIdx.x;
    const int lane = tid & 63, w = tid >> 6;
    const int l16 = lane & 15, h16 = lane >> 4;
    const int domask = maskp[0];

    __shared__ unsigned short KhS[64][72];
    __shared__ unsigned short KlS[64][72];
    __shared__ unsigned short VtS[64][72];   // [d][key]
    __shared__ unsigned short PsS[64][72];   // wave-private rows

    // Q fragments in registers (A-layout: row=l16, k=8*h16+e per 32-chunk)
    const int qrow = qb*64 + w*16 + l16;
    const size_t qoff = ((size_t)bh*T_ + qrow)*HD_ + 8*h16;
    const bf16x8 qh0 = *(const bf16x8*)(qhp + qoff);
    const bf16x8 qh1 = *(const bf16x8*)(qhp + qoff + 32);
    const bf16x8 ql0 = *(const bf16x8*)(qlp + qoff);
    const bf16x8 ql1 = *(const bf16x8*)(qlp + qoff + 32);

    f32x4 accO[4];
#pragma unroll
    for (int j=0;j<4;j++) accO[j] = (f32x4){0.f,0.f,0.f,0.f};
    float m_run[4], l_run[4];
#pragma unroll
    for (int i=0;i<4;i++){ m_run[i] = -INFINITY; l_run[i] = 0.f; }

    const int r   = tid >> 2;         // staging row 0..63
    const int c16 = (tid & 3) * 16;   // staging col base
    const size_t kbase = (size_t)bh*T_*HD_;
    const size_t vbase = (size_t)bh*HD_*T_;

    const int kv_end = domask ? qb : 31;
    for (int kv = 0; kv <= kv_end; ++kv){
        const unsigned short* ksrc = khp + kbase + (size_t)(kv*64+r)*HD_ + c16;
        uint4 a0 = *(const uint4*)(ksrc);
        uint4 a1 = *(const uint4*)(ksrc+8);
        const unsigned short* lsrc = klp + kbase + (size_t)(kv*64+r)*HD_ + c16;
        uint4 a2 = *(const uint4*)(lsrc);
        uint4 a3 = *(const uint4*)(lsrc+8);
        const unsigned short* vsrc = vtp + vbase + (size_t)r*T_ + kv*64 + c16;
        uint4 a4 = *(const uint4*)(vsrc);
        uint4 a5 = *(const uint4*)(vsrc+8);
        __syncthreads();   // prev tile reads done
        *(uint4*)&KhS[r][c16] = a0; *(uint4*)&KhS[r][c16+8] = a1;
        *(uint4*)&KlS[r][c16] = a2; *(uint4*)&KlS[r][c16+8] = a3;
        *(uint4*)&VtS[r][c16] = a4; *(uint4*)&VtS[r][c16+8] = a5;
        __syncthreads();

        // S = Q K^T  (split precision, small terms first)
        f32x4 s[4];
#pragma unroll
        for (int j=0;j<4;j++){
            const bf16x8 kh0 = *(const bf16x8*)&KhS[j*16+l16][8*h16];
            const bf16x8 kh1 = *(const bf16x8*)&KhS[j*16+l16][32+8*h16];
            const bf16x8 kl0 = *(const bf16x8*)&KlS[j*16+l16][8*h16];
            const bf16x8 kl1 = *(const bf16x8*)&KlS[j*16+l16][32+8*h16];
            f32x4 a = (f32x4){0.f,0.f,0.f,0.f};
            a = __builtin_amdgcn_mfma_f32_16x16x32_bf16(qh0, kl0, a, 0,0,0);
            a = __builtin_amdgcn_mfma_f32_16x16x32_bf16(ql0, kh0, a, 0,0,0);
            a = __builtin_amdgcn_mfma_f32_16x16x32_bf16(qh1, kl1, a, 0,0,0);
            a = __builtin_amdgcn_mfma_f32_16x16x32_bf16(ql1, kh1, a, 0,0,0);
            a = __builtin_amdgcn_mfma_f32_16x16x32_bf16(qh0, kh0, a, 0,0,0);
            a = __builtin_amdgcn_mfma_f32_16x16x32_bf16(qh1, kh1, a, 0,0,0);
            s[j] = a;
        }
        if (domask && kv == qb){
#pragma unroll
            for (int j=0;j<4;j++)
#pragma unroll
                for (int reg=0;reg<4;reg++)
                    if (j*16+l16 > w*16 + h16*4 + reg) s[j][reg] = -INFINITY;
        }

        // online softmax; rows = w*16 + h16*4 + reg, cols spread (j, l16)
#pragma unroll
        for (int reg=0; reg<4; ++reg){
            float mloc = fmaxf(fmaxf(s[0][reg],s[1][reg]), fmaxf(s[2][reg],s[3][reg]));
            mloc = fmaxf(mloc, __shfl_xor(mloc,1));
            mloc = fmaxf(mloc, __shfl_xor(mloc,2));
            mloc = fmaxf(mloc, __shfl_xor(mloc,4));
            mloc = fmaxf(mloc, __shfl_xor(mloc,8));
            float mnew = fmaxf(m_run[reg], mloc);
            float scl  = __expf(m_run[reg] - mnew);   // exp(-inf)=0 first tile
            m_run[reg] = mnew;
            float p0 = __expf(s[0][reg]-mnew);
            float p1 = __expf(s[1][reg]-mnew);
            float p2 = __expf(s[2][reg]-mnew);
            float p3 = __expf(s[3][reg]-mnew);
            float rs = p0+p1+p2+p3;
            rs += __shfl_xor(rs,1); rs += __shfl_xor(rs,2);
            rs += __shfl_xor(rs,4); rs += __shfl_xor(rs,8);
            l_run[reg] = l_run[reg]*scl + rs;
            accO[0][reg] *= scl; accO[1][reg] *= scl;
            accO[2][reg] *= scl; accO[3][reg] *= scl;
            const int prow = w*16 + h16*4 + reg;
            PsS[prow][ 0+l16] = f2bf(p0);
            PsS[prow][16+l16] = f2bf(p1);
            PsS[prow][32+l16] = f2bf(p2);
            PsS[prow][48+l16] = f2bf(p3);
        }

        // O += P V  (PsS rows are wave-private; same-wave RAW via lgkmcnt)
#pragma unroll
        for (int c=0;c<2;c++){
            const bf16x8 pa = *(const bf16x8*)&PsS[w*16+l16][c*32+8*h16];
#pragma unroll
            for (int j=0;j<4;j++){
                const bf16x8 vb_ = *(const bf16x8*)&VtS[j*16+l16][c*32+8*h16];
                accO[j] = __builtin_amdgcn_mfma_f32_16x16x32_bf16(pa, vb_, accO[j], 0,0,0);
            }
        }
    }

    // epilogue: D-layout row = w*16+h16*4+reg, col d = j*16+l16
#pragma unroll
    for (int reg=0;reg<4;reg++){
        const float inv = 1.0f / l_run[reg];
        const int t = qb*64 + w*16 + h16*4 + reg;
#pragma unroll
        for (int j=0;j<4;j++){
            attb[((size_t)b*T_ + t)*D_ + h*HD_ + j*16 + l16] =
                f2bf(accO[j][reg]*inv);
        }
    }
}

extern "C" void kernel_launch(void* const* d_in, const int* in_sizes, int n_in,
                              void* d_out, int out_size, void* d_ws, size_t ws_size,
                              hipStream_t stream)
{
    const float* x  = (const float*)d_in[0];
    const float* Wq = (const float*)d_in[1];
    const float* bq = (const float*)d_in[2];
    const float* Wk = (const float*)d_in[3];
    const float* bk = (const float*)d_in[4];
    const float* Wv = (const float*)d_in[5];
    const float* bv = (const float*)d_in[6];
    const float* Wo = (const float*)d_in[7];
    const float* bo = (const float*)d_in[8];
    const int* mask = (const int*)d_in[9];
    float* out = (float*)d_out;

    // workspace (126 MiB): all bf16
    unsigned short* qhp = (unsigned short*)d_ws;                 // 16 MiB
    unsigned short* qlp = qhp + (size_t)8*1024*1024;             // 16 MiB
    unsigned short* khp = qlp + (size_t)8*1024*1024;             // 16 MiB
    unsigned short* klp = khp + (size_t)8*1024*1024;             // 16 MiB
    unsigned short* vtp = klp + (size_t)8*1024*1024;             // 16 MiB [bh][d][t]
    unsigned short* xh  = vtp + (size_t)8*1024*1024;             // 16 MiB
    unsigned short* xl  = xh  + (size_t)8*1024*1024;             // 16 MiB
    unsigned short* wh  = xl  + (size_t)8*1024*1024;             // 6 MiB
    unsigned short* wl  = wh  + (size_t)3*1024*1024;             // 6 MiB
    unsigned short* wot = wl  + (size_t)3*1024*1024;             // 2 MiB
    unsigned short* attb = xh;   // alias: xh dead after gemm_qkv3

    prep_x2   <<<2048, 256, 0, stream>>>(x, xh, xl);
    prep_wqkv2<<<dim3(16,48), 256, 0, stream>>>(Wq, Wk, Wv, wh, wl);
    prep_wo   <<<dim3(16,16), 256, 0, stream>>>(Wo, wot);
    gemm_qkv3 <<<dim3(64,24), 256, 0, stream>>>(xh, xl, wh, wl, bq, bk, bv,
                                                qhp, qlp, khp, klp, vtp);
    attn_mfma <<<2048, 256, 0, stream>>>(qhp, qlp, khp, klp, vtp, attb, mask);
    gemm_o    <<<dim3(64,8), 256, 0, stream>>>(attb, wot, bo, out);
}

// Round 10
// 318.721 us; speedup vs baseline: 6.9499x; 1.0335x over previous
//
#include <hip/hip_runtime.h>
#include <hip/hip_bf16.h>
#include <math.h>

#define B_  4
#define T_  2048
#define D_  1024
#define H_  16
#define HD_ 64
#define M_  8192   // B_*T_

typedef __attribute__((ext_vector_type(8))) short bf16x8;
typedef __attribute__((ext_vector_type(4))) float f32x4;

static __device__ __forceinline__ unsigned short f2bf(float f){
    unsigned int u = __float_as_uint(f);
    unsigned int r = u + 0x7FFFu + ((u >> 16) & 1u);   // RNE
    return (unsigned short)(r >> 16);
}
static __device__ __forceinline__ float bfbits2f(unsigned short s){
    return __uint_as_float(((unsigned int)s) << 16);
}
static __device__ __forceinline__ void gload_lds16(const void* g, void* l){
    __builtin_amdgcn_global_load_lds(
        (const __attribute__((address_space(1))) unsigned int*)g,
        (__attribute__((address_space(3))) unsigned int*)l, 16, 0, 0);
}

union U16x16 { unsigned short us[16]; uint4 q[2]; };
union U16x4  { unsigned short us[4];  uint2 q;    };

// ---------------------------------------------------------------------------
// prep_x2: x fp32 -> xh (bf16 hi) + xl (bf16 residual). 16 el/thread.
// ---------------------------------------------------------------------------
__global__ __launch_bounds__(256) void prep_x2(
    const float* __restrict__ x,
    unsigned short* __restrict__ xh, unsigned short* __restrict__ xl)
{
    const size_t i = ((size_t)blockIdx.x*256 + threadIdx.x)*16;
    U16x16 uh, ul;
#pragma unroll
    for (int j=0;j<16;j+=4){
        float4 f = *(const float4*)(x+i+j);
        float v[4] = {f.x,f.y,f.z,f.w};
#pragma unroll
        for (int k=0;k<4;k++){
            unsigned short hb = f2bf(v[k]);
            uh.us[j+k] = hb;
            ul.us[j+k] = f2bf(v[k] - bfbits2f(hb));
        }
    }
    *(uint4*)(xh+i)   = uh.q[0]; *(uint4*)(xh+i+8) = uh.q[1];
    *(uint4*)(xl+i)   = ul.q[0]; *(uint4*)(xl+i+8) = ul.q[1];
}

// ---------------------------------------------------------------------------
// prep_wqkv2: W{q,k,v}[16][1024][64] -> wt_hi/wt_lo[3072][1024] (operand-major).
// ---------------------------------------------------------------------------
__global__ __launch_bounds__(256) void prep_wqkv2(
    const float* __restrict__ Wq, const float* __restrict__ Wk,
    const float* __restrict__ Wv,
    unsigned short* __restrict__ wh, unsigned short* __restrict__ wl)
{
    const int dt = blockIdx.x;
    const int zh = blockIdx.y;
    const int z = zh >> 4, h = zh & 15;
    const float* src = ((z==0)?Wq:(z==1)?Wk:Wv) + (size_t)h*1024*64;
    __shared__ float Tt[64][68];
    const int t = threadIdx.x;
    const int r = t >> 2, c4 = (t & 3) * 16;
    const float* sp = src + (size_t)(dt*64 + r)*64 + c4;
    float4 v0=*(const float4*)(sp+0), v1=*(const float4*)(sp+4);
    float4 v2=*(const float4*)(sp+8), v3=*(const float4*)(sp+12);
    *(float4*)&Tt[r][c4+ 0]=v0; *(float4*)&Tt[r][c4+ 4]=v1;
    *(float4*)&Tt[r][c4+ 8]=v2; *(float4*)&Tt[r][c4+12]=v3;
    __syncthreads();
    const int er = t >> 2, dk = (t & 3) * 16;
    U16x16 uh, ul;
#pragma unroll
    for (int j=0;j<16;j++){
        float v = Tt[dk+j][er];
        unsigned short hb = f2bf(v);
        uh.us[j] = hb;
        ul.us[j] = f2bf(v - bfbits2f(hb));
    }
    size_t off = (size_t)(z*1024 + h*64 + er)*1024 + dt*64 + dk;
    *(uint4*)(wh+off)   = uh.q[0]; *(uint4*)(wh+off+8) = uh.q[1];
    *(uint4*)(wl+off)   = ul.q[0]; *(uint4*)(wl+off+8) = ul.q[1];
}

// ---------------------------------------------------------------------------
// prep_wo: Wo[1024][1024] -> wot[n][k] bf16 (hi only).
// ---------------------------------------------------------------------------
__global__ __launch_bounds__(256) void prep_wo(
    const float* __restrict__ Wo, unsigned short* __restrict__ wot)
{
    const int kt = blockIdx.x, nt = blockIdx.y;
    __shared__ float Tt[64][68];
    const int t = threadIdx.x;
    const int r = t >> 2, c4 = (t & 3) * 16;
    const float* sp = Wo + (size_t)(kt*64 + r)*1024 + nt*64 + c4;
    float4 v0=*(const float4*)(sp+0), v1=*(const float4*)(sp+4);
    float4 v2=*(const float4*)(sp+8), v3=*(const float4*)(sp+12);
    *(float4*)&Tt[r][c4+ 0]=v0; *(float4*)&Tt[r][c4+ 4]=v1;
    *(float4*)&Tt[r][c4+ 8]=v2; *(float4*)&Tt[r][c4+12]=v3;
    __syncthreads();
    const int er = t >> 2, dk = (t & 3) * 16;
    U16x16 u;
#pragma unroll
    for (int j=0;j<16;j++) u.us[j] = f2bf(Tt[dk+j][er]);
    unsigned short* dst = wot + (size_t)(nt*64 + er)*1024 + kt*64 + dk;
    *(uint4*)(dst)   = u.q[0];
    *(uint4*)(dst+8) = u.q[1];
}

// ---------------------------------------------------------------------------
// gemm_qkv3: C[128x128]/block, 4 waves, 64x64/wave, bf16 16x16x32 MFMA.
// Staging: global_load_lds(16B) direct to linear [128][32]-short LDS buffers,
// chunk-XOR swizzle (phys = c ^ ((row>>1)&3)) applied via pre-swizzled global
// source; fragment reads use lane-uniform key (fla>>1)&3 -> 2-way (free) banks.
// Split-precision (hi*hi+hi*lo+lo*hi) for q,k (n0<2048) -> qh/ql, kh/kl.
// v: single product, output bf16 TRANSPOSED [bh][d][t] via uint2 stores.
// ---------------------------------------------------------------------------
__global__ __launch_bounds__(256) void gemm_qkv3(
    const unsigned short* __restrict__ xh, const unsigned short* __restrict__ xl,
    const unsigned short* __restrict__ wh, const unsigned short* __restrict__ wl,
    const float* __restrict__ bqv, const float* __restrict__ bkv,
    const float* __restrict__ bvv,
    unsigned short* __restrict__ qhp, unsigned short* __restrict__ qlp,
    unsigned short* __restrict__ khp, unsigned short* __restrict__ klp,
    unsigned short* __restrict__ vtp)
{
    const int m0 = blockIdx.x * 128;
    const int n0 = blockIdx.y * 128;
    const bool precise = (n0 < 2048);   // q,k need split precision
    const int tid = threadIdx.x;
    const int lane = tid & 63, w = tid >> 6;
    const int wr = w >> 1, wc = w & 1;
    const int fla = lane & 15, flb = lane >> 4;

    __shared__ unsigned short Ah[128*32];
    __shared__ unsigned short Bh[128*32];
    __shared__ unsigned short Al[128*32];
    __shared__ unsigned short Bl[128*32];

    f32x4 acc[4][4];
#pragma unroll
    for (int i=0;i<4;i++)
#pragma unroll
        for (int j=0;j<4;j++) acc[i][j] = (f32x4){0.f,0.f,0.f,0.f};

    // staging geometry: inst (q=0,1) covers LDS bytes [w*2048+q*1024, +1024)
    // lane covers row = w*32+q*16+lane/4, phys chunk = lane&3,
    // logical chunk = pc ^ ((row>>1)&3); global src = row-major + logical chunk.
    const int srow0 = w*32 + (lane>>2);
    const int srow1 = srow0 + 16;
    const int spc   = lane & 3;
    const size_t ga0 = (size_t)(m0+srow0)*1024 + (size_t)((spc ^ ((srow0>>1)&3))*8);
    const size_t ga1 = (size_t)(m0+srow1)*1024 + (size_t)((spc ^ ((srow1>>1)&3))*8);
    const size_t gb0 = (size_t)(n0+srow0)*1024 + (size_t)((spc ^ ((srow0>>1)&3))*8);
    const size_t gb1 = (size_t)(n0+srow1)*1024 + (size_t)((spc ^ ((srow1>>1)&3))*8);
    const int ldso0 = w*1024;          // shorts
    const int ldso1 = w*1024 + 512;

    // fragment read offset: row r -> key (r>>1)&3 == (fla>>1)&3 (tile-row aligned)
    const int pchunk = (flb ^ ((fla>>1)&3)) * 8;

    for (int ks = 0; ks < 32; ++ks){
        const size_t k0 = (size_t)ks*32;
        __syncthreads();   // prev chunk's fragment reads complete
        gload_lds16(xh + ga0 + k0, Ah + ldso0);
        gload_lds16(xh + ga1 + k0, Ah + ldso1);
        gload_lds16(wh + gb0 + k0, Bh + ldso0);
        gload_lds16(wh + gb1 + k0, Bh + ldso1);
        if (precise){
            gload_lds16(xl + ga0 + k0, Al + ldso0);
            gload_lds16(xl + ga1 + k0, Al + ldso1);
            gload_lds16(wl + gb0 + k0, Bl + ldso0);
            gload_lds16(wl + gb1 + k0, Bl + ldso1);
        }
        __syncthreads();   // vmcnt(0) drained before barrier (compiler)

        bf16x8 afh[4], bfh[4];
#pragma unroll
        for (int mf=0; mf<4; ++mf)
            afh[mf] = *(const bf16x8*)&Ah[(wr*64+mf*16+fla)*32 + pchunk];
#pragma unroll
        for (int nf=0; nf<4; ++nf)
            bfh[nf] = *(const bf16x8*)&Bh[(wc*64+nf*16+fla)*32 + pchunk];
        if (precise){
            bf16x8 afl[4], bfl[4];
#pragma unroll
            for (int mf=0; mf<4; ++mf)
                afl[mf] = *(const bf16x8*)&Al[(wr*64+mf*16+fla)*32 + pchunk];
#pragma unroll
            for (int nf=0; nf<4; ++nf)
                bfl[nf] = *(const bf16x8*)&Bl[(wc*64+nf*16+fla)*32 + pchunk];
#pragma unroll
            for (int mf=0; mf<4; ++mf)
#pragma unroll
                for (int nf=0; nf<4; ++nf){
                    acc[mf][nf] = __builtin_amdgcn_mfma_f32_16x16x32_bf16(
                                      afh[mf], bfl[nf], acc[mf][nf], 0, 0, 0);
                    acc[mf][nf] = __builtin_amdgcn_mfma_f32_16x16x32_bf16(
                                      afl[mf], bfh[nf], acc[mf][nf], 0, 0, 0);
                    acc[mf][nf] = __builtin_amdgcn_mfma_f32_16x16x32_bf16(
                                      afh[mf], bfh[nf], acc[mf][nf], 0, 0, 0);
                }
        } else {
#pragma unroll
            for (int mf=0; mf<4; ++mf)
#pragma unroll
                for (int nf=0; nf<4; ++nf)
                    acc[mf][nf] = __builtin_amdgcn_mfma_f32_16x16x32_bf16(
                                      afh[mf], bfh[nf], acc[mf][nf], 0, 0, 0);
        }
    }

    if (precise){
#pragma unroll
        for (int nf=0; nf<4; ++nf){
            const int c = n0 + wc*64 + nf*16 + fla;
            const int z = c >> 10, rem = c & 1023;
            const int h = rem >> 6, e = rem & 63;
            const float bias = ((z==0)?bqv:bkv)[rem];
            const float scl  = (z==0) ? 8.0f : 1.0f;
            unsigned short* oh = (z==0)?qhp:khp;
            unsigned short* ol = (z==0)?qlp:klp;
#pragma unroll
            for (int mf=0; mf<4; ++mf){
#pragma unroll
                for (int ri=0; ri<4; ++ri){
                    const int m = m0 + wr*64 + mf*16 + flb*4 + ri;
                    const int b = m >> 11, t = m & (T_-1);
                    const float val = (acc[mf][nf][ri] + bias) * scl;
                    const unsigned short hb = f2bf(val);
                    const size_t idx = ((size_t)(b*H_ + h)*T_ + t)*HD_ + e;
                    oh[idx] = hb;
                    ol[idx] = f2bf(val - bfbits2f(hb));
                }
            }
        }
    } else {
#pragma unroll
        for (int nf=0; nf<4; ++nf){
            const int c = n0 + wc*64 + nf*16 + fla;
            const int rem = c & 1023;
            const int h = rem >> 6, e = rem & 63;
            const float bias = bvv[rem];
#pragma unroll
            for (int mf=0; mf<4; ++mf){
                const int m = m0 + wr*64 + mf*16 + flb*4;   // 4 consecutive t
                const int b = m >> 11, t = m & (T_-1);
                U16x4 u;
#pragma unroll
                for (int ri=0; ri<4; ++ri)
                    u.us[ri] = f2bf(acc[mf][nf][ri] + bias);
                *(uint2*)(vtp + ((size_t)(b*H_ + h)*HD_ + e)*T_ + t) = u.q;
            }
        }
    }
}

#define KPAD 40
// ---------------------------------------------------------------------------
// gemm_o: out = att(bf16) @ wot(bf16) + bo. (unchanged)
// ---------------------------------------------------------------------------
__global__ __launch_bounds__(256) void gemm_o(
    const unsigned short* __restrict__ attb, const unsigned short* __restrict__ wot,
    const float* __restrict__ bo, float* __restrict__ out)
{
    const int m0 = blockIdx.x * 128;
    const int n0 = blockIdx.y * 128;
    const int tid = threadIdx.x;
    const int lane = tid & 63, wid = tid >> 6;
    const int wr = wid >> 1, wc = wid & 1;
    const int fla = lane & 15, flb = lane >> 4;

    __shared__ unsigned short As[128*KPAD];
    __shared__ unsigned short Bs[128*KPAD];

    f32x4 acc[4][4];
#pragma unroll
    for (int i=0;i<4;i++)
#pragma unroll
        for (int j=0;j<4;j++) acc[i][j] = (f32x4){0.f,0.f,0.f,0.f};

    const int sr = tid >> 1, sh = tid & 1;
    const unsigned short* ap = attb + (size_t)(m0+sr)*1024 + sh*16;
    const unsigned short* bp = wot  + (size_t)(n0+sr)*1024 + sh*16;
    unsigned short* asd = &As[sr*KPAD + sh*16];
    unsigned short* bsd = &Bs[sr*KPAD + sh*16];

    for (int ks = 0; ks < 32; ++ks){
        uint4 a0 = *(const uint4*)(ap + ks*32);
        uint4 a1 = *(const uint4*)(ap + ks*32 + 8);
        uint4 b0 = *(const uint4*)(bp + ks*32);
        uint4 b1 = *(const uint4*)(bp + ks*32 + 8);
        __syncthreads();
        *(uint4*)(asd)   = a0; *(uint4*)(asd+8) = a1;
        *(uint4*)(bsd)   = b0; *(uint4*)(bsd+8) = b1;
        __syncthreads();
        bf16x8 af[4], bfr[4];
#pragma unroll
        for (int mf=0; mf<4; ++mf)
            af[mf] = *(const bf16x8*)&As[(wr*64+mf*16+fla)*KPAD + flb*8];
#pragma unroll
        for (int nf=0; nf<4; ++nf)
            bfr[nf] = *(const bf16x8*)&Bs[(wc*64+nf*16+fla)*KPAD + flb*8];
#pragma unroll
        for (int mf=0; mf<4; ++mf)
#pragma unroll
            for (int nf=0; nf<4; ++nf)
                acc[mf][nf] = __builtin_amdgcn_mfma_f32_16x16x32_bf16(
                                  af[mf], bfr[nf], acc[mf][nf], 0, 0, 0);
    }

#pragma unroll
    for (int nf=0; nf<4; ++nf){
        const int n = n0 + wc*64 + nf*16 + fla;
        const float bias = bo[n];
#pragma unroll
        for (int mf=0; mf<4; ++mf){
#pragma unroll
            for (int ri=0; ri<4; ++ri){
                const int m = m0 + wr*64 + mf*16 + flb*4 + ri;
                out[(size_t)m*D_ + n] = acc[mf][nf][ri] + bias;
            }
        }
    }
}

// ---------------------------------------------------------------------------
// MFMA flash attention. (unchanged from round 9)
// ---------------------------------------------------------------------------
__global__ __launch_bounds__(256) void attn_mfma(
    const unsigned short* __restrict__ qhp, const unsigned short* __restrict__ qlp,
    const unsigned short* __restrict__ khp, const unsigned short* __restrict__ klp,
    const unsigned short* __restrict__ vtp, unsigned short* __restrict__ attb,
    const int* __restrict__ maskp)
{
    const int bid = blockIdx.x;
    const int qb  = 31 - (bid >> 6);   // big blocks first
    const int bh  = bid & 63;
    const int b   = bh >> 4, h = bh & 15;
    const int tid = threadIdx.x;
    const int lane = tid & 63, w = tid >> 6;
    const int l16 = lane & 15, h16 = lane >> 4;
    const int domask = maskp[0];

    __shared__ unsigned short KhS[64][72];
    __shared__ unsigned short KlS[64][72];
    __shared__ unsigned short VtS[64][72];   // [d][key]
    __shared__ unsigned short PsS[64][72];   // wave-private rows

    const int qrow = qb*64 + w*16 + l16;
    const size_t qoff = ((size_t)bh*T_ + qrow)*HD_ + 8*h16;
    const bf16x8 qh0 = *(const bf16x8*)(qhp + qoff);
    const bf16x8 qh1 = *(const bf16x8*)(qhp + qoff + 32);
    const bf16x8 ql0 = *(const bf16x8*)(qlp + qoff);
    const bf16x8 ql1 = *(const bf16x8*)(qlp + qoff + 32);

    f32x4 accO[4];
#pragma unroll
    for (int j=0;j<4;j++) accO[j] = (f32x4){0.f,0.f,0.f,0.f};
    float m_run[4], l_run[4];
#pragma unroll
    for (int i=0;i<4;i++){ m_run[i] = -INFINITY; l_run[i] = 0.f; }

    const int r   = tid >> 2;         // staging row 0..63
    const int c16 = (tid & 3) * 16;   // staging col base
    const size_t kbase = (size_t)bh*T_*HD_;
    const size_t vbase = (size_t)bh*HD_*T_;

    const int kv_end = domask ? qb : 31;
    for (int kv = 0; kv <= kv_end; ++kv){
        const unsigned short* ksrc = khp + kbase + (size_t)(kv*64+r)*HD_ + c16;
        uint4 a0 = *(const uint4*)(ksrc);
        uint4 a1 = *(const uint4*)(ksrc+8);
        const unsigned short* lsrc = klp + kbase + (size_t)(kv*64+r)*HD_ + c16;
        uint4 a2 = *(const uint4*)(lsrc);
        uint4 a3 = *(const uint4*)(lsrc+8);
        const unsigned short* vsrc = vtp + vbase + (size_t)r*T_ + kv*64 + c16;
        uint4 a4 = *(const uint4*)(vsrc);
        uint4 a5 = *(const uint4*)(vsrc+8);
        __syncthreads();   // prev tile reads done
        *(uint4*)&KhS[r][c16] = a0; *(uint4*)&KhS[r][c16+8] = a1;
        *(uint4*)&KlS[r][c16] = a2; *(uint4*)&KlS[r][c16+8] = a3;
        *(uint4*)&VtS[r][c16] = a4; *(uint4*)&VtS[r][c16+8] = a5;
        __syncthreads();

        // S = Q K^T  (split precision, small terms first)
        f32x4 s[4];
#pragma unroll
        for (int j=0;j<4;j++){
            const bf16x8 kh0 = *(const bf16x8*)&KhS[j*16+l16][8*h16];
            const bf16x8 kh1 = *(const bf16x8*)&KhS[j*16+l16][32+8*h16];
            const bf16x8 kl0 = *(const bf16x8*)&KlS[j*16+l16][8*h16];
            const bf16x8 kl1 = *(const bf16x8*)&KlS[j*16+l16][32+8*h16];
            f32x4 a = (f32x4){0.f,0.f,0.f,0.f};
            a = __builtin_amdgcn_mfma_f32_16x16x32_bf16(qh0, kl0, a, 0,0,0);
            a = __builtin_amdgcn_mfma_f32_16x16x32_bf16(ql0, kh0, a, 0,0,0);
            a = __builtin_amdgcn_mfma_f32_16x16x32_bf16(qh1, kl1, a, 0,0,0);
            a = __builtin_amdgcn_mfma_f32_16x16x32_bf16(ql1, kh1, a, 0,0,0);
            a = __builtin_amdgcn_mfma_f32_16x16x32_bf16(qh0, kh0, a, 0,0,0);
            a = __builtin_amdgcn_mfma_f32_16x16x32_bf16(qh1, kh1, a, 0,0,0);
            s[j] = a;
        }
        if (domask && kv == qb){
#pragma unroll
            for (int j=0;j<4;j++)
#pragma unroll
                for (int reg=0;reg<4;reg++)
                    if (j*16+l16 > w*16 + h16*4 + reg) s[j][reg] = -INFINITY;
        }

        // online softmax; rows = w*16 + h16*4 + reg
#pragma unroll
        for (int reg=0; reg<4; ++reg){
            float mloc = fmaxf(fmaxf(s[0][reg],s[1][reg]), fmaxf(s[2][reg],s[3][reg]));
            mloc = fmaxf(mloc, __shfl_xor(mloc,1));
            mloc = fmaxf(mloc, __shfl_xor(mloc,2));
            mloc = fmaxf(mloc, __shfl_xor(mloc,4));
            mloc = fmaxf(mloc, __shfl_xor(mloc,8));
            float mnew = fmaxf(m_run[reg], mloc);
            float scl  = __expf(m_run[reg] - mnew);   // exp(-inf)=0 first tile
            m_run[reg] = mnew;
            float p0 = __expf(s[0][reg]-mnew);
            float p1 = __expf(s[1][reg]-mnew);
            float p2 = __expf(s[2][reg]-mnew);
            float p3 = __expf(s[3][reg]-mnew);
            float rs = p0+p1+p2+p3;
            rs += __shfl_xor(rs,1); rs += __shfl_xor(rs,2);
            rs += __shfl_xor(rs,4); rs += __shfl_xor(rs,8);
            l_run[reg] = l_run[reg]*scl + rs;
            accO[0][reg] *= scl; accO[1][reg] *= scl;
            accO[2][reg] *= scl; accO[3][reg] *= scl;
            const int prow = w*16 + h16*4 + reg;
            PsS[prow][ 0+l16] = f2bf(p0);
            PsS[prow][16+l16] = f2bf(p1);
            PsS[prow][32+l16] = f2bf(p2);
            PsS[prow][48+l16] = f2bf(p3);
        }

        // O += P V  (PsS rows wave-private)
#pragma unroll
        for (int c=0;c<2;c++){
            const bf16x8 pa = *(const bf16x8*)&PsS[w*16+l16][c*32+8*h16];
#pragma unroll
            for (int j=0;j<4;j++){
                const bf16x8 vb_ = *(const bf16x8*)&VtS[j*16+l16][c*32+8*h16];
                accO[j] = __builtin_amdgcn_mfma_f32_16x16x32_bf16(pa, vb_, accO[j], 0,0,0);
            }
        }
    }

#pragma unroll
    for (int reg=0;reg<4;reg++){
        const float inv = 1.0f / l_run[reg];
        const int t = qb*64 + w*16 + h16*4 + reg;
#pragma unroll
        for (int j=0;j<4;j++){
            attb[((size_t)b*T_ + t)*D_ + h*HD_ + j*16 + l16] =
                f2bf(accO[j][reg]*inv);
        }
    }
}

extern "C" void kernel_launch(void* const* d_in, const int* in_sizes, int n_in,
                              void* d_out, int out_size, void* d_ws, size_t ws_size,
                              hipStream_t stream)
{
    const float* x  = (const float*)d_in[0];
    const float* Wq = (const float*)d_in[1];
    const float* bq = (const float*)d_in[2];
    const float* Wk = (const float*)d_in[3];
    const float* bk = (const float*)d_in[4];
    const float* Wv = (const float*)d_in[5];
    const float* bv = (const float*)d_in[6];
    const float* Wo = (const float*)d_in[7];
    const float* bo = (const float*)d_in[8];
    const int* mask = (const int*)d_in[9];
    float* out = (float*)d_out;

    // workspace (126 MiB): all bf16
    unsigned short* qhp = (unsigned short*)d_ws;                 // 16 MiB
    unsigned short* qlp = qhp + (size_t)8*1024*1024;             // 16 MiB
    unsigned short* khp = qlp + (size_t)8*1024*1024;             // 16 MiB
    unsigned short* klp = khp + (size_t)8*1024*1024;             // 16 MiB
    unsigned short* vtp = klp + (size_t)8*1024*1024;             // 16 MiB [bh][d][t]
    unsigned short* xh  = vtp + (size_t)8*1024*1024;             // 16 MiB
    unsigned short* xl  = xh  + (size_t)8*1024*1024;             // 16 MiB
    unsigned short* wh  = xl  + (size_t)8*1024*1024;             // 6 MiB
    unsigned short* wl  = wh  + (size_t)3*1024*1024;             // 6 MiB
    unsigned short* wot = wl  + (size_t)3*1024*1024;             // 2 MiB
    unsigned short* attb = xh;   // alias: xh dead after gemm_qkv3

    prep_x2   <<<2048, 256, 0, stream>>>(x, xh, xl);
    prep_wqkv2<<<dim3(16,48), 256, 0, stream>>>(Wq, Wk, Wv, wh, wl);
    prep_wo   <<<dim3(16,16), 256, 0, stream>>>(Wo, wot);
    gemm_qkv3 <<<dim3(64,24), 256, 0, stream>>>(xh, xl, wh, wl, bq, bk, bv,
                                                qhp, qlp, khp, klp, vtp);
    attn_mfma <<<2048, 256, 0, stream>>>(qhp, qlp, khp, klp, vtp, attb, mask);
    gemm_o    <<<dim3(64,8), 256, 0, stream>>>(attb, wot, bo, out);
}